// Round 6
// baseline (544.703 us; speedup 1.0000x reference)
//
#include <hip/hip_runtime.h>

#define D 128
#define SCAN_CHUNK 1024
#define NCHUNK 8
#define BPC 32        // edge-slices (blocks) per chunk
#define CS_MAX 12544  // max nodes per chunk (LDS: 50176 B)

typedef __attribute__((ext_vector_type(8))) short bf16x8;
typedef __attribute__((ext_vector_type(16))) float f32x16;

__device__ inline float b2f(unsigned int hi16_as_lo) {
  union { unsigned int u; float f; } v;
  v.u = hi16_as_lo;
  return v.f;
}
__device__ inline unsigned short f2b(float f) {  // RNE f32 -> bf16
  union { float f; unsigned int u; } v;
  v.f = f;
  unsigned int r = v.u + 0x7FFFu + ((v.u >> 16) & 1u);
  return (unsigned short)(r >> 16);
}
__device__ inline unsigned int pk2(float lo, float hi) {
  return (unsigned int)f2b(lo) | ((unsigned int)f2b(hi) << 16);
}

// ---------------------------------------------------------------------------
// f32 -> bf16 convert (8 elems/thread)
// ---------------------------------------------------------------------------
__global__ __launch_bounds__(256) void convert_kernel(
    const float* __restrict__ in, unsigned short* __restrict__ out, int n8) {
  int i = blockIdx.x * 256 + threadIdx.x;
  if (i >= n8) return;
  const float4 a = *reinterpret_cast<const float4*>(in + (size_t)i * 8);
  const float4 b = *reinterpret_cast<const float4*>(in + (size_t)i * 8 + 4);
  unsigned short o[8] = {f2b(a.x), f2b(a.y), f2b(a.z), f2b(a.w),
                         f2b(b.x), f2b(b.y), f2b(b.z), f2b(b.w)};
  *reinterpret_cast<bf16x8*>(out + (size_t)i * 8) =
      *reinterpret_cast<bf16x8*>(o);
}

// ---------------------------------------------------------------------------
// Pack all 6 W (128x128 f32, row-major fan_in x fan_out) into MFMA fragment
// order: lane l, tile t, step s holds W[s*16+(l>>5)*8+i][t*32+(l&31)].
// One launch, 48 blocks (6 matrices x 8 blocks).
// ---------------------------------------------------------------------------
__global__ __launch_bounds__(256) void pack_w6_kernel(
    const float* __restrict__ w0, const float* __restrict__ w1,
    const float* __restrict__ w2, const float* __restrict__ w3,
    const float* __restrict__ w4, const float* __restrict__ w5,
    unsigned short* __restrict__ Wp) {
  const int m = blockIdx.x >> 3;
  const float* W = m == 0 ? w0
                 : m == 1 ? w1
                 : m == 2 ? w2
                 : m == 3 ? w3
                 : m == 4 ? w4
                          : w5;
  const int idx = (blockIdx.x & 7) * 256 + threadIdx.x;  // 0..2047
  const int l = idx & 63;
  const int s = (idx >> 6) & 7;
  const int t = idx >> 9;
  const int n = (t << 5) + (l & 31);
  const int k0 = (s << 4) + ((l >> 5) << 3);
  unsigned short o[8];
#pragma unroll
  for (int i = 0; i < 8; ++i) o[i] = f2b(W[(size_t)(k0 + i) * D + n]);
  *reinterpret_cast<bf16x8*>(Wp + (size_t)m * 16384 + (size_t)idx * 8) =
      *reinterpret_cast<bf16x8*>(o);
}

// ---------------------------------------------------------------------------
// Atomic-free CSR build:
//   histC : LDS histogram per (chunk, edge-slice) block  -> partial
//   scanS : per node, prefix over the 32 slices          -> bofs, cnt
//   scanA/B/C : exclusive scan of cnt                    -> rowptr
//   fillC : LDS cursor = rowptr+bofs; place src          -> col
// Only LDS atomics; chunk c pinned to XCD c via blockIdx&7.
// ---------------------------------------------------------------------------
__global__ __launch_bounds__(256) void histC_kernel(
    const int* __restrict__ dst, int* __restrict__ partial, int n_edges,
    int n_nodes, int CS, int slice) {
  __shared__ int hist[CS_MAX];
  const int c = blockIdx.x & 7;
  const int b = blockIdx.x >> 3;
  const int lo = c * CS;
  const int hi = min(lo + CS, n_nodes);
  const int len = hi - lo;
  for (int i = threadIdx.x; i < len; i += 256) hist[i] = 0;
  __syncthreads();
  const int e1 = min((b + 1) * slice, n_edges);
  for (int e = b * slice + threadIdx.x; e < e1; e += 256) {
    const int d = dst[e];
    if (d >= lo && d < hi) atomicAdd(&hist[d - lo], 1);
  }
  __syncthreads();
  int* out = partial + (size_t)(c * BPC + b) * CS;
  for (int i = threadIdx.x; i < len; i += 256) out[i] = hist[i];
}

__global__ __launch_bounds__(256) void scanS_kernel(
    const int* __restrict__ partial, int* __restrict__ bofs,
    int* __restrict__ cnt, int n_nodes, int CS) {
  const int n = blockIdx.x * 256 + threadIdx.x;
  if (n >= n_nodes) return;
  const int c = n / CS;
  const int i = n - c * CS;
  int run = 0;
#pragma unroll 8
  for (int b = 0; b < BPC; ++b) {
    const size_t idx = (size_t)(c * BPC + b) * CS + i;
    const int v = partial[idx];
    bofs[idx] = run;
    run += v;
  }
  cnt[n] = run;
}

__global__ __launch_bounds__(256) void scanA_kernel(
    const int* __restrict__ cnt, int* __restrict__ rowptr,
    int* __restrict__ chunkSums, int n) {
  __shared__ int lds[256];
  const int t = threadIdx.x;
  const int idx = blockIdx.x * SCAN_CHUNK + t * 4;
  int4 v = make_int4(0, 0, 0, 0);
  if (idx < n) v = *reinterpret_cast<const int4*>(cnt + idx);
  const int s = v.x + v.y + v.z + v.w;
  lds[t] = s;
  __syncthreads();
#pragma unroll
  for (int off = 1; off < 256; off <<= 1) {
    int p = 0;
    if (t >= off) p = lds[t - off];
    __syncthreads();
    lds[t] += p;
    __syncthreads();
  }
  const int excl = lds[t] - s;
  if (idx < n) {
    int4 o;
    o.x = excl;
    o.y = excl + v.x;
    o.z = o.y + v.y;
    o.w = o.z + v.z;
    *reinterpret_cast<int4*>(rowptr + idx) = o;
  }
  if (t == 255) chunkSums[blockIdx.x] = lds[255];
}

__global__ __launch_bounds__(256) void scanB_kernel(int* __restrict__ chunkSums,
                                                    int n_chunks) {
  __shared__ int lds[256];
  const int t = threadIdx.x;
  const int v = (t < n_chunks) ? chunkSums[t] : 0;
  lds[t] = v;
  __syncthreads();
#pragma unroll
  for (int off = 1; off < 256; off <<= 1) {
    int p = 0;
    if (t >= off) p = lds[t - off];
    __syncthreads();
    lds[t] += p;
    __syncthreads();
  }
  if (t < n_chunks) chunkSums[t] = lds[t] - v;
}

__global__ __launch_bounds__(256) void scanC_kernel(
    int* __restrict__ rowptr, const int* __restrict__ chunkSums, int n_nodes,
    int n_edges) {
  int i = blockIdx.x * 256 + threadIdx.x;
  if (i < n_nodes) rowptr[i] += chunkSums[i / SCAN_CHUNK];
  if (i == n_nodes) rowptr[n_nodes] = n_edges;
}

__global__ __launch_bounds__(256) void fillC_kernel(
    const int* __restrict__ src, const int* __restrict__ dst,
    const int* __restrict__ rowptr, const int* __restrict__ bofs,
    int* __restrict__ col, int n_edges, int n_nodes, int CS, int slice) {
  __shared__ int cursor[CS_MAX];
  const int c = blockIdx.x & 7;
  const int b = blockIdx.x >> 3;
  const int lo = c * CS;
  const int hi = min(lo + CS, n_nodes);
  const int len = hi - lo;
  const int* bo = bofs + (size_t)(c * BPC + b) * CS;
  for (int i = threadIdx.x; i < len; i += 256)
    cursor[i] = rowptr[lo + i] + bo[i];
  __syncthreads();
  const int e1 = min((b + 1) * slice, n_edges);
  for (int e = b * slice + threadIdx.x; e < e1; e += 256) {
    const int d = dst[e];
    if (d >= lo && d < hi) {
      const int pos = atomicAdd(&cursor[d - lo], 1);
      col[pos] = src[e];
    }
  }
}

// ---------------------------------------------------------------------------
// Gather aggregation (bf16): out[n] = X[n] + sum_{j} X[col[j]]
// 32 lanes/node, 8 B per lane; unrolled x4; f32 accumulate.
// ---------------------------------------------------------------------------
__global__ __launch_bounds__(256) void gather_bf16_kernel(
    const unsigned short* __restrict__ X, const int* __restrict__ rowptr,
    const int* __restrict__ col, unsigned short* __restrict__ out,
    int n_nodes) {
  int g = (blockIdx.x * 256 + threadIdx.x) >> 5;
  if (g >= n_nodes) return;
  const int c = threadIdx.x & 31;
  const uint2* Xv = reinterpret_cast<const uint2*>(X);
  uint2 u = Xv[(size_t)g * 32 + c];  // self term
  float a0 = b2f(u.x << 16), a1 = b2f(u.x & 0xffff0000u);
  float a2 = b2f(u.y << 16), a3 = b2f(u.y & 0xffff0000u);
  const int beg = rowptr[g], end = rowptr[g + 1];
  int j = beg;
  for (; j + 4 <= end; j += 4) {
    const int s0 = col[j + 0];
    const int s1 = col[j + 1];
    const int s2 = col[j + 2];
    const int s3 = col[j + 3];
    const uint2 w0 = Xv[(size_t)s0 * 32 + c];
    const uint2 w1 = Xv[(size_t)s1 * 32 + c];
    const uint2 w2 = Xv[(size_t)s2 * 32 + c];
    const uint2 w3 = Xv[(size_t)s3 * 32 + c];
    a0 += b2f(w0.x << 16); a1 += b2f(w0.x & 0xffff0000u);
    a2 += b2f(w0.y << 16); a3 += b2f(w0.y & 0xffff0000u);
    a0 += b2f(w1.x << 16); a1 += b2f(w1.x & 0xffff0000u);
    a2 += b2f(w1.y << 16); a3 += b2f(w1.y & 0xffff0000u);
    a0 += b2f(w2.x << 16); a1 += b2f(w2.x & 0xffff0000u);
    a2 += b2f(w2.y << 16); a3 += b2f(w2.y & 0xffff0000u);
    a0 += b2f(w3.x << 16); a1 += b2f(w3.x & 0xffff0000u);
    a2 += b2f(w3.y << 16); a3 += b2f(w3.y & 0xffff0000u);
  }
  for (; j < end; ++j) {
    const uint2 w = Xv[(size_t)col[j] * 32 + c];
    a0 += b2f(w.x << 16); a1 += b2f(w.x & 0xffff0000u);
    a2 += b2f(w.y << 16); a3 += b2f(w.y & 0xffff0000u);
  }
  uint2 o;
  o.x = pk2(a0, a1);
  o.y = pk2(a2, a3);
  reinterpret_cast<uint2*>(out)[(size_t)g * 32 + c] = o;
}

// ---------------------------------------------------------------------------
// Fused MLP pair: out = [relu]( relu(S@W1+b1) @ W2 + b2 ), bf16 io, f32 acc.
// Both GEMMs transposed orientation; handoff + store via cvt-pack + shfl.
// ---------------------------------------------------------------------------
template <int RELU>
__global__ __launch_bounds__(256) void mlp2_kernel(
    const unsigned short* __restrict__ X, const unsigned short* __restrict__ Wp1,
    const unsigned short* __restrict__ Wp2, const float* __restrict__ bias1,
    const float* __restrict__ bias2, unsigned short* __restrict__ out,
    int n_strips) {
  __shared__ unsigned short wl1[16384];  // 32 KB
  __shared__ unsigned short wl2[16384];  // 32 KB
  __shared__ float bl1[128], bl2[128];
  for (int i = threadIdx.x * 8; i < 16384; i += 256 * 8) {
    *reinterpret_cast<bf16x8*>(wl1 + i) = *reinterpret_cast<const bf16x8*>(Wp1 + i);
    *reinterpret_cast<bf16x8*>(wl2 + i) = *reinterpret_cast<const bf16x8*>(Wp2 + i);
  }
  if (threadIdx.x < 128) {
    bl1[threadIdx.x] = bias1[threadIdx.x];
    bl2[threadIdx.x] = bias2[threadIdx.x];
  }
  __syncthreads();

  const int lx = threadIdx.x & 63;
  const int h = lx >> 5;
  const int nl = lx & 31;  // node-local index
  const int gwave = blockIdx.x * 4 + (threadIdx.x >> 6);
  const int nwaves = gridDim.x * 4;

  for (int strip = gwave; strip < n_strips; strip += nwaves) {
    const unsigned short* xrow = X + (size_t)(strip * 32 + nl) * D + h * 8;
    bf16x8 xf[8];
#pragma unroll
    for (int s = 0; s < 8; ++s)
      xf[s] = *reinterpret_cast<const bf16x8*>(xrow + s * 16);

    f32x16 acc1[4];
#pragma unroll
    for (int t1 = 0; t1 < 4; ++t1)
#pragma unroll
      for (int r = 0; r < 16; ++r)
        acc1[t1][r] = bl1[32 * t1 + (r & 3) + 8 * (r >> 2) + 4 * h];
#pragma unroll
    for (int s = 0; s < 8; ++s) {
#pragma unroll
      for (int t1 = 0; t1 < 4; ++t1) {
        const bf16x8 wf = *reinterpret_cast<const bf16x8*>(
            wl1 + ((t1 * 8 + s) * 64 + lx) * 8);
        acc1[t1] = __builtin_amdgcn_mfma_f32_32x32x16_bf16(wf, xf[s], acc1[t1],
                                                           0, 0, 0);
      }
    }

    f32x16 acc2[4];
#pragma unroll
    for (int t = 0; t < 4; ++t)
#pragma unroll
      for (int r = 0; r < 16; ++r)
        acc2[t][r] = bl2[32 * t + (r & 3) + 8 * (r >> 2) + 4 * h];
#pragma unroll
    for (int s2 = 0; s2 < 8; ++s2) {
      const int t1 = s2 >> 1;
      const int ro = (s2 & 1) << 3;
      const float g0 = fmaxf(acc1[t1][ro + 0], 0.f);
      const float g1 = fmaxf(acc1[t1][ro + 1], 0.f);
      const float g2 = fmaxf(acc1[t1][ro + 2], 0.f);
      const float g3 = fmaxf(acc1[t1][ro + 3], 0.f);
      const float g4 = fmaxf(acc1[t1][ro + 4], 0.f);
      const float g5 = fmaxf(acc1[t1][ro + 5], 0.f);
      const float g6 = fmaxf(acc1[t1][ro + 6], 0.f);
      const float g7 = fmaxf(acc1[t1][ro + 7], 0.f);
      const unsigned int pA0 = pk2(g0, g1), pA1 = pk2(g2, g3);
      const unsigned int pB0 = pk2(g4, g5), pB1 = pk2(g6, g7);
      const unsigned int sA0 = (unsigned int)__shfl((int)pA0, lx ^ 32, 64);
      const unsigned int sA1 = (unsigned int)__shfl((int)pA1, lx ^ 32, 64);
      const unsigned int sB0 = (unsigned int)__shfl((int)pB0, lx ^ 32, 64);
      const unsigned int sB1 = (unsigned int)__shfl((int)pB1, lx ^ 32, 64);
      union { unsigned int u[4]; bf16x8 v; } fr;
      fr.u[0] = h ? sB0 : pA0;
      fr.u[1] = h ? sB1 : pA1;
      fr.u[2] = h ? pB0 : sA0;
      fr.u[3] = h ? pB1 : sA1;
#pragma unroll
      for (int t = 0; t < 4; ++t) {
        const bf16x8 wf = *reinterpret_cast<const bf16x8*>(
            wl2 + ((t * 8 + s2) * 64 + lx) * 8);
        acc2[t] = __builtin_amdgcn_mfma_f32_32x32x16_bf16(wf, fr.v, acc2[t],
                                                          0, 0, 0);
      }
    }

    unsigned short* orow = out + (size_t)(strip * 32 + nl) * D + h * 8;
#pragma unroll
    for (int s = 0; s < 8; ++s) {
      const int t = s >> 1;
      const int ro = (s & 1) << 3;
      float g0 = acc2[t][ro + 0], g1 = acc2[t][ro + 1];
      float g2 = acc2[t][ro + 2], g3 = acc2[t][ro + 3];
      float g4 = acc2[t][ro + 4], g5 = acc2[t][ro + 5];
      float g6 = acc2[t][ro + 6], g7 = acc2[t][ro + 7];
      if (RELU) {
        g0 = fmaxf(g0, 0.f); g1 = fmaxf(g1, 0.f);
        g2 = fmaxf(g2, 0.f); g3 = fmaxf(g3, 0.f);
        g4 = fmaxf(g4, 0.f); g5 = fmaxf(g5, 0.f);
        g6 = fmaxf(g6, 0.f); g7 = fmaxf(g7, 0.f);
      }
      const unsigned int pA0 = pk2(g0, g1), pA1 = pk2(g2, g3);
      const unsigned int pB0 = pk2(g4, g5), pB1 = pk2(g6, g7);
      const unsigned int sA0 = (unsigned int)__shfl((int)pA0, lx ^ 32, 64);
      const unsigned int sA1 = (unsigned int)__shfl((int)pA1, lx ^ 32, 64);
      const unsigned int sB0 = (unsigned int)__shfl((int)pB0, lx ^ 32, 64);
      const unsigned int sB1 = (unsigned int)__shfl((int)pB1, lx ^ 32, 64);
      union { unsigned int u[4]; bf16x8 v; } fr;
      fr.u[0] = h ? sB0 : pA0;
      fr.u[1] = h ? sB1 : pA1;
      fr.u[2] = h ? pB0 : sA0;
      fr.u[3] = h ? pB1 : sA1;
      *reinterpret_cast<bf16x8*>(orow + s * 16) = fr.v;
    }
  }
}

// ---------------------------------------------------------------------------
// Global mean pool (batch sorted): run-length accumulate, atomic flush per run.
// ---------------------------------------------------------------------------
#define POOL_NODES_PER_GROUP 128

__global__ __launch_bounds__(256) void pool_kernel(
    const unsigned short* __restrict__ H, const int* __restrict__ batch,
    float* __restrict__ sums, float* __restrict__ counts, int n_nodes) {
  const int group = (blockIdx.x * 256 + threadIdx.x) >> 5;
  const int lane = threadIdx.x & 31;
  const int n0 = group * POOL_NODES_PER_GROUP;
  if (n0 >= n_nodes) return;
  const int n1 = min(n0 + POOL_NODES_PER_GROUP, n_nodes);
  const uint2* Hv = reinterpret_cast<const uint2*>(H);

  float a0 = 0.f, a1 = 0.f, a2 = 0.f, a3 = 0.f;
  int cur = batch[n0];
  int runlen = 0;
  for (int n = n0; n < n1; ++n) {
    const int g = batch[n];
    if (g != cur) {
      float* p = sums + (size_t)cur * D + lane * 4;
      unsafeAtomicAdd(p + 0, a0);
      unsafeAtomicAdd(p + 1, a1);
      unsafeAtomicAdd(p + 2, a2);
      unsafeAtomicAdd(p + 3, a3);
      if (lane == 0) unsafeAtomicAdd(counts + cur, (float)runlen);
      a0 = a1 = a2 = a3 = 0.f;
      cur = g;
      runlen = 0;
    }
    const uint2 v = Hv[(size_t)n * 32 + lane];
    a0 += b2f(v.x << 16);
    a1 += b2f(v.x & 0xffff0000u);
    a2 += b2f(v.y << 16);
    a3 += b2f(v.y & 0xffff0000u);
    ++runlen;
  }
  float* p = sums + (size_t)cur * D + lane * 4;
  unsafeAtomicAdd(p + 0, a0);
  unsafeAtomicAdd(p + 1, a1);
  unsafeAtomicAdd(p + 2, a2);
  unsafeAtomicAdd(p + 3, a3);
  if (lane == 0) unsafeAtomicAdd(counts + cur, (float)runlen);
}

__global__ __launch_bounds__(256) void pool_norm_kernel(
    float* __restrict__ out, const float* __restrict__ counts, int n) {
  int i = blockIdx.x * 256 + threadIdx.x;
  if (i >= n) return;
  float cnt = counts[i / D];
  out[i] = out[i] / fmaxf(cnt, 1.0f);
}

// ---------------------------------------------------------------------------
extern "C" void kernel_launch(void* const* d_in, const int* in_sizes, int n_in,
                              void* d_out, int out_size, void* d_ws,
                              size_t ws_size, hipStream_t stream) {
  const float* x = (const float*)d_in[0];
  const int* ei = (const int*)d_in[1];
  const int* batch = (const int*)d_in[2];
  const float* B[6] = {(const float*)d_in[4],  (const float*)d_in[6],
                       (const float*)d_in[8],  (const float*)d_in[10],
                       (const float*)d_in[12], (const float*)d_in[14]};

  const int n_nodes = in_sizes[2];
  const int n_edges = in_sizes[1] / 2;
  const int n_graphs = out_size / D;
  const int* src = ei;
  const int* dst = ei + n_edges;

  const size_t matB = (size_t)n_nodes * D * sizeof(unsigned short);  // 25.6 MB
  unsigned short* bufA = (unsigned short*)d_ws;
  unsigned short* bufB = (unsigned short*)((char*)d_ws + matB);
  unsigned short* bufC = (unsigned short*)((char*)d_ws + 2 * matB);
  unsigned short* wpack = (unsigned short*)((char*)d_ws + 3 * matB);
  int* rowptr = (int*)((char*)wpack + 6 * 16384 * sizeof(unsigned short));
  int* cnt = rowptr + (n_nodes + 1);
  int* colidx = cnt + n_nodes;
  const int CS = (n_nodes + NCHUNK - 1) / NCHUNK;  // 12500
  int* partial = colidx + n_edges;                  // 8*32*CS ints (12.8 MB)
  int* bofs = partial + (size_t)NCHUNK * BPC * CS;  // 12.8 MB
  int* chunkSums = bofs + (size_t)NCHUNK * BPC * CS;
  float* counts = (float*)(chunkSums + 256);

  const dim3 blk(256);
  const int n_chunks = (n_nodes + SCAN_CHUNK - 1) / SCAN_CHUNK;
  const int gather_blocks = (int)(((long long)n_nodes * 32 + 255) / 256);
  const int pool_groups =
      (n_nodes + POOL_NODES_PER_GROUP - 1) / POOL_NODES_PER_GROUP;
  const int pool_blocks = (pool_groups * 32 + 255) / 256;
  const int n_strips = n_nodes / 32;  // 100000 % 32 == 0
  const int mlp_grid = 512;           // 2 blocks/CU at 64 KB LDS
  const int slice = (n_edges + BPC - 1) / BPC;
  const int node_blocks = (n_nodes + 255) / 256;

  // ---- precompute: convert x, pack weights, build CSR (atomic-free) ----
  convert_kernel<<<(n_nodes * (D / 8) + 255) / 256, blk, 0, stream>>>(
      x, bufA, n_nodes * (D / 8));
  pack_w6_kernel<<<48, blk, 0, stream>>>(
      (const float*)d_in[3], (const float*)d_in[5], (const float*)d_in[7],
      (const float*)d_in[9], (const float*)d_in[11], (const float*)d_in[13],
      wpack);

  histC_kernel<<<NCHUNK * BPC, blk, 0, stream>>>(dst, partial, n_edges,
                                                 n_nodes, CS, slice);
  scanS_kernel<<<node_blocks, blk, 0, stream>>>(partial, bofs, cnt, n_nodes,
                                                CS);
  scanA_kernel<<<n_chunks, blk, 0, stream>>>(cnt, rowptr, chunkSums, n_nodes);
  scanB_kernel<<<1, blk, 0, stream>>>(chunkSums, n_chunks);
  scanC_kernel<<<(n_nodes + 256) / 256, blk, 0, stream>>>(rowptr, chunkSums,
                                                          n_nodes, n_edges);
  fillC_kernel<<<NCHUNK * BPC, blk, 0, stream>>>(src, dst, rowptr, bofs,
                                                 colidx, n_edges, n_nodes, CS,
                                                 slice);

  // ---- layer 1 ----
  gather_bf16_kernel<<<gather_blocks, blk, 0, stream>>>(bufA, rowptr, colidx,
                                                        bufB, n_nodes);
  mlp2_kernel<1><<<mlp_grid, blk, 0, stream>>>(bufB, wpack + 0 * 16384,
                                               wpack + 1 * 16384, B[0], B[1],
                                               bufC, n_strips);
  // ---- layer 2 ----
  gather_bf16_kernel<<<gather_blocks, blk, 0, stream>>>(bufC, rowptr, colidx,
                                                        bufB, n_nodes);
  mlp2_kernel<1><<<mlp_grid, blk, 0, stream>>>(bufB, wpack + 2 * 16384,
                                               wpack + 3 * 16384, B[2], B[3],
                                               bufA, n_strips);
  // ---- layer 3 ----
  gather_bf16_kernel<<<gather_blocks, blk, 0, stream>>>(bufA, rowptr, colidx,
                                                        bufB, n_nodes);
  mlp2_kernel<0><<<mlp_grid, blk, 0, stream>>>(bufB, wpack + 4 * 16384,
                                               wpack + 5 * 16384, B[4], B[5],
                                               bufC, n_strips);

  // ---- global mean pool ----
  hipMemsetAsync(d_out, 0, (size_t)out_size * sizeof(float), stream);
  hipMemsetAsync(counts, 0, (size_t)n_graphs * sizeof(float), stream);
  pool_kernel<<<pool_blocks, blk, 0, stream>>>(bufC, batch, (float*)d_out,
                                               counts, n_nodes);
  pool_norm_kernel<<<(out_size + 255) / 256, blk, 0, stream>>>((float*)d_out,
                                                               counts,
                                                               out_size);
}

// Round 7
// 427.373 us; speedup vs baseline: 1.2745x; 1.2745x over previous
//
#include <hip/hip_runtime.h>

#define D 128
#define SCAN_CHUNK 1024
#define FILL_EPB 2048

typedef __attribute__((ext_vector_type(8))) short bf16x8;
typedef __attribute__((ext_vector_type(16))) float f32x16;

__device__ inline float b2f(unsigned int hi16_as_lo) {
  union { unsigned int u; float f; } v;
  v.u = hi16_as_lo;
  return v.f;
}
__device__ inline unsigned short f2b(float f) {  // RNE f32 -> bf16
  union { float f; unsigned int u; } v;
  v.f = f;
  unsigned int r = v.u + 0x7FFFu + ((v.u >> 16) & 1u);
  return (unsigned short)(r >> 16);
}
__device__ inline unsigned int pk2(float lo, float hi) {
  return (unsigned int)f2b(lo) | ((unsigned int)f2b(hi) << 16);
}

// ---------------------------------------------------------------------------
// f32 -> bf16 convert (8 elems/thread)
// ---------------------------------------------------------------------------
__global__ __launch_bounds__(256) void convert_kernel(
    const float* __restrict__ in, unsigned short* __restrict__ out, int n8) {
  int i = blockIdx.x * 256 + threadIdx.x;
  if (i >= n8) return;
  const float4 a = *reinterpret_cast<const float4*>(in + (size_t)i * 8);
  const float4 b = *reinterpret_cast<const float4*>(in + (size_t)i * 8 + 4);
  unsigned short o[8] = {f2b(a.x), f2b(a.y), f2b(a.z), f2b(a.w),
                         f2b(b.x), f2b(b.y), f2b(b.z), f2b(b.w)};
  *reinterpret_cast<bf16x8*>(out + (size_t)i * 8) =
      *reinterpret_cast<bf16x8*>(o);
}

// ---------------------------------------------------------------------------
// Pack all 6 W (128x128 f32, row-major fan_in x fan_out) into MFMA fragment
// order: lane l, tile t, step s holds W[s*16+(l>>5)*8+i][t*32+(l&31)].
// ---------------------------------------------------------------------------
__global__ __launch_bounds__(256) void pack_w6_kernel(
    const float* __restrict__ w0, const float* __restrict__ w1,
    const float* __restrict__ w2, const float* __restrict__ w3,
    const float* __restrict__ w4, const float* __restrict__ w5,
    unsigned short* __restrict__ Wp) {
  const int m = blockIdx.x >> 3;
  const float* W = m == 0 ? w0
                 : m == 1 ? w1
                 : m == 2 ? w2
                 : m == 3 ? w3
                 : m == 4 ? w4
                          : w5;
  const int idx = (blockIdx.x & 7) * 256 + threadIdx.x;  // 0..2047
  const int l = idx & 63;
  const int s = (idx >> 6) & 7;
  const int t = idx >> 9;
  const int n = (t << 5) + (l & 31);
  const int k0 = (s << 4) + ((l >> 5) << 3);
  unsigned short o[8];
#pragma unroll
  for (int i = 0; i < 8; ++i) o[i] = f2b(W[(size_t)(k0 + i) * D + n]);
  *reinterpret_cast<bf16x8*>(Wp + (size_t)m * 16384 + (size_t)idx * 8) =
      *reinterpret_cast<bf16x8*>(o);
}

// ---------------------------------------------------------------------------
// CSR build (R5 config): histogram (+rank capture) -> scan -> atomic-free fill
// ---------------------------------------------------------------------------
__global__ __launch_bounds__(256) void hist_kernel(
    const int* __restrict__ dst, int* __restrict__ cnt,
    unsigned short* __restrict__ rank, int n_edges) {
  int e = blockIdx.x * 256 + threadIdx.x;
  if (e < n_edges) rank[e] = (unsigned short)atomicAdd(&cnt[dst[e]], 1);
}

__global__ __launch_bounds__(256) void scanA_kernel(
    const int* __restrict__ cnt, int* __restrict__ rowptr,
    int* __restrict__ chunkSums, int n) {
  __shared__ int lds[256];
  const int t = threadIdx.x;
  const int idx = blockIdx.x * SCAN_CHUNK + t * 4;
  int4 v = make_int4(0, 0, 0, 0);
  if (idx < n) v = *reinterpret_cast<const int4*>(cnt + idx);
  const int s = v.x + v.y + v.z + v.w;
  lds[t] = s;
  __syncthreads();
#pragma unroll
  for (int off = 1; off < 256; off <<= 1) {
    int p = 0;
    if (t >= off) p = lds[t - off];
    __syncthreads();
    lds[t] += p;
    __syncthreads();
  }
  const int excl = lds[t] - s;
  if (idx < n) {
    int4 o;
    o.x = excl;
    o.y = excl + v.x;
    o.z = o.y + v.y;
    o.w = o.z + v.z;
    *reinterpret_cast<int4*>(rowptr + idx) = o;
  }
  if (t == 255) chunkSums[blockIdx.x] = lds[255];
}

__global__ __launch_bounds__(256) void scanB_kernel(int* __restrict__ chunkSums,
                                                    int n_chunks) {
  __shared__ int lds[256];
  const int t = threadIdx.x;
  const int v = (t < n_chunks) ? chunkSums[t] : 0;
  lds[t] = v;
  __syncthreads();
#pragma unroll
  for (int off = 1; off < 256; off <<= 1) {
    int p = 0;
    if (t >= off) p = lds[t - off];
    __syncthreads();
    lds[t] += p;
    __syncthreads();
  }
  if (t < n_chunks) chunkSums[t] = lds[t] - v;
}

__global__ __launch_bounds__(256) void scanC_kernel(
    int* __restrict__ rowptr, const int* __restrict__ chunkSums, int n_nodes,
    int n_edges) {
  int i = blockIdx.x * 256 + threadIdx.x;
  if (i < n_nodes) rowptr[i] += chunkSums[i / SCAN_CHUNK];
  if (i == n_nodes) rowptr[n_nodes] = n_edges;
}

// Atomic-free partitioned fill: pos = rowptr[dst] + rank. Partition
// p=blockIdx&7 writes only its 1/8 node range -> col lines stay in one L2.
__global__ __launch_bounds__(256) void fill_kernel(
    const int* __restrict__ src, const int* __restrict__ dst,
    const unsigned short* __restrict__ rank, const int* __restrict__ rowptr,
    int* __restrict__ col, int n_edges, int npart) {
  const int p = blockIdx.x & 7;
  const int chunk = blockIdx.x >> 3;
  const int lo = p * npart;
  const int hi = lo + npart;
  const int e1 = min((chunk + 1) * FILL_EPB, n_edges);
  for (int e = chunk * FILL_EPB + threadIdx.x; e < e1; e += 256) {
    const int d = dst[e];
    if (d >= lo && d < hi) col[rowptr[d] + (int)rank[e]] = src[e];
  }
}

// ---------------------------------------------------------------------------
// Gather aggregation (bf16): out[n] = X[n] + sum_{j} X[col[j]]
// 16 lanes/node, 16 B (uint4) per lane -> 4 nodes per wave; unrolled x4.
// ---------------------------------------------------------------------------
__global__ __launch_bounds__(256) void gather_bf16_kernel(
    const unsigned short* __restrict__ X, const int* __restrict__ rowptr,
    const int* __restrict__ col, unsigned short* __restrict__ out,
    int n_nodes) {
  const int t = blockIdx.x * 256 + threadIdx.x;
  const int g = t >> 4;
  if (g >= n_nodes) return;
  const int c = t & 15;
  const uint4* Xv = reinterpret_cast<const uint4*>(X);
  const uint4 u = Xv[(size_t)g * 16 + c];  // self term
  float a0 = b2f(u.x << 16), a1 = b2f(u.x & 0xffff0000u);
  float a2 = b2f(u.y << 16), a3 = b2f(u.y & 0xffff0000u);
  float a4 = b2f(u.z << 16), a5 = b2f(u.z & 0xffff0000u);
  float a6 = b2f(u.w << 16), a7 = b2f(u.w & 0xffff0000u);
  const int beg = rowptr[g], end = rowptr[g + 1];
  int j = beg;
  for (; j + 4 <= end; j += 4) {
    const int s0 = col[j + 0];
    const int s1 = col[j + 1];
    const int s2 = col[j + 2];
    const int s3 = col[j + 3];
    const uint4 w0 = Xv[(size_t)s0 * 16 + c];
    const uint4 w1 = Xv[(size_t)s1 * 16 + c];
    const uint4 w2 = Xv[(size_t)s2 * 16 + c];
    const uint4 w3 = Xv[(size_t)s3 * 16 + c];
    a0 += b2f(w0.x << 16); a1 += b2f(w0.x & 0xffff0000u);
    a2 += b2f(w0.y << 16); a3 += b2f(w0.y & 0xffff0000u);
    a4 += b2f(w0.z << 16); a5 += b2f(w0.z & 0xffff0000u);
    a6 += b2f(w0.w << 16); a7 += b2f(w0.w & 0xffff0000u);
    a0 += b2f(w1.x << 16); a1 += b2f(w1.x & 0xffff0000u);
    a2 += b2f(w1.y << 16); a3 += b2f(w1.y & 0xffff0000u);
    a4 += b2f(w1.z << 16); a5 += b2f(w1.z & 0xffff0000u);
    a6 += b2f(w1.w << 16); a7 += b2f(w1.w & 0xffff0000u);
    a0 += b2f(w2.x << 16); a1 += b2f(w2.x & 0xffff0000u);
    a2 += b2f(w2.y << 16); a3 += b2f(w2.y & 0xffff0000u);
    a4 += b2f(w2.z << 16); a5 += b2f(w2.z & 0xffff0000u);
    a6 += b2f(w2.w << 16); a7 += b2f(w2.w & 0xffff0000u);
    a0 += b2f(w3.x << 16); a1 += b2f(w3.x & 0xffff0000u);
    a2 += b2f(w3.y << 16); a3 += b2f(w3.y & 0xffff0000u);
    a4 += b2f(w3.z << 16); a5 += b2f(w3.z & 0xffff0000u);
    a6 += b2f(w3.w << 16); a7 += b2f(w3.w & 0xffff0000u);
  }
  for (; j < end; ++j) {
    const uint4 w = Xv[(size_t)col[j] * 16 + c];
    a0 += b2f(w.x << 16); a1 += b2f(w.x & 0xffff0000u);
    a2 += b2f(w.y << 16); a3 += b2f(w.y & 0xffff0000u);
    a4 += b2f(w.z << 16); a5 += b2f(w.z & 0xffff0000u);
    a6 += b2f(w.w << 16); a7 += b2f(w.w & 0xffff0000u);
  }
  uint4 o;
  o.x = pk2(a0, a1);
  o.y = pk2(a2, a3);
  o.z = pk2(a4, a5);
  o.w = pk2(a6, a7);
  reinterpret_cast<uint4*>(out)[(size_t)g * 16 + c] = o;
}

// ---------------------------------------------------------------------------
// Fused MLP pair: out = [relu]( relu(S@W1+b1) @ W2 + b2 ), bf16 io, f32 acc.
// 512-thread blocks (8 waves), each wave owns ONE 32-row strip. xf global
// loads issued BEFORE W staging so HBM latency hides under stage+barrier.
// ---------------------------------------------------------------------------
template <int RELU>
__global__ __launch_bounds__(512) void mlp2_kernel(
    const unsigned short* __restrict__ X, const unsigned short* __restrict__ Wp1,
    const unsigned short* __restrict__ Wp2, const float* __restrict__ bias1,
    const float* __restrict__ bias2, unsigned short* __restrict__ out,
    int n_strips) {
  __shared__ unsigned short wl1[16384];  // 32 KB
  __shared__ unsigned short wl2[16384];  // 32 KB
  __shared__ float bl1[128], bl2[128];

  const int lx = threadIdx.x & 63;
  const int wid = threadIdx.x >> 6;
  const int strip = blockIdx.x * 8 + wid;
  const int h = lx >> 5;
  const int nl = lx & 31;

  // issue xf loads first (overlap with staging)
  bf16x8 xf[8];
  if (strip < n_strips) {
    const unsigned short* xrow = X + (size_t)(strip * 32 + nl) * D + h * 8;
#pragma unroll
    for (int s = 0; s < 8; ++s)
      xf[s] = *reinterpret_cast<const bf16x8*>(xrow + s * 16);
  }

  for (int i = threadIdx.x * 8; i < 16384; i += 512 * 8) {
    *reinterpret_cast<bf16x8*>(wl1 + i) = *reinterpret_cast<const bf16x8*>(Wp1 + i);
    *reinterpret_cast<bf16x8*>(wl2 + i) = *reinterpret_cast<const bf16x8*>(Wp2 + i);
  }
  if (threadIdx.x < 128) {
    bl1[threadIdx.x] = bias1[threadIdx.x];
    bl2[threadIdx.x] = bias2[threadIdx.x];
  }
  __syncthreads();
  if (strip >= n_strips) return;

  // ---- GEMM1: acc1 = W1^T @ X^T tile, init with bias1 ----
  f32x16 acc1[4];
#pragma unroll
  for (int t1 = 0; t1 < 4; ++t1)
#pragma unroll
    for (int r = 0; r < 16; ++r)
      acc1[t1][r] = bl1[32 * t1 + (r & 3) + 8 * (r >> 2) + 4 * h];
#pragma unroll
  for (int s = 0; s < 8; ++s) {
#pragma unroll
    for (int t1 = 0; t1 < 4; ++t1) {
      const bf16x8 wf = *reinterpret_cast<const bf16x8*>(
          wl1 + ((t1 * 8 + s) * 64 + lx) * 8);
      acc1[t1] =
          __builtin_amdgcn_mfma_f32_32x32x16_bf16(wf, xf[s], acc1[t1], 0, 0, 0);
    }
  }

  // ---- handoff T^T -> A2 frags; GEMM2 ----
  f32x16 acc2[4];
#pragma unroll
  for (int t = 0; t < 4; ++t)
#pragma unroll
    for (int r = 0; r < 16; ++r)
      acc2[t][r] = bl2[32 * t + (r & 3) + 8 * (r >> 2) + 4 * h];
#pragma unroll
  for (int s2 = 0; s2 < 8; ++s2) {
    const int t1 = s2 >> 1;
    const int ro = (s2 & 1) << 3;
    const float g0 = fmaxf(acc1[t1][ro + 0], 0.f);
    const float g1 = fmaxf(acc1[t1][ro + 1], 0.f);
    const float g2 = fmaxf(acc1[t1][ro + 2], 0.f);
    const float g3 = fmaxf(acc1[t1][ro + 3], 0.f);
    const float g4 = fmaxf(acc1[t1][ro + 4], 0.f);
    const float g5 = fmaxf(acc1[t1][ro + 5], 0.f);
    const float g6 = fmaxf(acc1[t1][ro + 6], 0.f);
    const float g7 = fmaxf(acc1[t1][ro + 7], 0.f);
    const unsigned int pA0 = pk2(g0, g1), pA1 = pk2(g2, g3);
    const unsigned int pB0 = pk2(g4, g5), pB1 = pk2(g6, g7);
    const unsigned int sA0 = (unsigned int)__shfl((int)pA0, lx ^ 32, 64);
    const unsigned int sA1 = (unsigned int)__shfl((int)pA1, lx ^ 32, 64);
    const unsigned int sB0 = (unsigned int)__shfl((int)pB0, lx ^ 32, 64);
    const unsigned int sB1 = (unsigned int)__shfl((int)pB1, lx ^ 32, 64);
    union { unsigned int u[4]; bf16x8 v; } fr;
    fr.u[0] = h ? sB0 : pA0;
    fr.u[1] = h ? sB1 : pA1;
    fr.u[2] = h ? pB0 : sA0;
    fr.u[3] = h ? pB1 : sA1;
#pragma unroll
    for (int t = 0; t < 4; ++t) {
      const bf16x8 wf = *reinterpret_cast<const bf16x8*>(
          wl2 + ((t * 8 + s2) * 64 + lx) * 8);
      acc2[t] =
          __builtin_amdgcn_mfma_f32_32x32x16_bf16(wf, fr.v, acc2[t], 0, 0, 0);
    }
  }

  // ---- epilogue: out^T -> row frags, 16B stores ----
  unsigned short* orow = out + (size_t)(strip * 32 + nl) * D + h * 8;
#pragma unroll
  for (int s = 0; s < 8; ++s) {
    const int t = s >> 1;
    const int ro = (s & 1) << 3;
    float g0 = acc2[t][ro + 0], g1 = acc2[t][ro + 1];
    float g2 = acc2[t][ro + 2], g3 = acc2[t][ro + 3];
    float g4 = acc2[t][ro + 4], g5 = acc2[t][ro + 5];
    float g6 = acc2[t][ro + 6], g7 = acc2[t][ro + 7];
    if (RELU) {
      g0 = fmaxf(g0, 0.f); g1 = fmaxf(g1, 0.f);
      g2 = fmaxf(g2, 0.f); g3 = fmaxf(g3, 0.f);
      g4 = fmaxf(g4, 0.f); g5 = fmaxf(g5, 0.f);
      g6 = fmaxf(g6, 0.f); g7 = fmaxf(g7, 0.f);
    }
    const unsigned int pA0 = pk2(g0, g1), pA1 = pk2(g2, g3);
    const unsigned int pB0 = pk2(g4, g5), pB1 = pk2(g6, g7);
    const unsigned int sA0 = (unsigned int)__shfl((int)pA0, lx ^ 32, 64);
    const unsigned int sA1 = (unsigned int)__shfl((int)pA1, lx ^ 32, 64);
    const unsigned int sB0 = (unsigned int)__shfl((int)pB0, lx ^ 32, 64);
    const unsigned int sB1 = (unsigned int)__shfl((int)pB1, lx ^ 32, 64);
    union { unsigned int u[4]; bf16x8 v; } fr;
    fr.u[0] = h ? sB0 : pA0;
    fr.u[1] = h ? sB1 : pA1;
    fr.u[2] = h ? pB0 : sA0;
    fr.u[3] = h ? pB1 : sA1;
    *reinterpret_cast<bf16x8*>(orow + s * 16) = fr.v;
  }
}

// ---------------------------------------------------------------------------
// Global mean pool (batch sorted): run-length accumulate, atomic flush per run.
// ---------------------------------------------------------------------------
#define POOL_NODES_PER_GROUP 128

__global__ __launch_bounds__(256) void pool_kernel(
    const unsigned short* __restrict__ H, const int* __restrict__ batch,
    float* __restrict__ sums, float* __restrict__ counts, int n_nodes) {
  const int group = (blockIdx.x * 256 + threadIdx.x) >> 5;
  const int lane = threadIdx.x & 31;
  const int n0 = group * POOL_NODES_PER_GROUP;
  if (n0 >= n_nodes) return;
  const int n1 = min(n0 + POOL_NODES_PER_GROUP, n_nodes);
  const uint2* Hv = reinterpret_cast<const uint2*>(H);

  float a0 = 0.f, a1 = 0.f, a2 = 0.f, a3 = 0.f;
  int cur = batch[n0];
  int runlen = 0;
  for (int n = n0; n < n1; ++n) {
    const int g = batch[n];
    if (g != cur) {
      float* p = sums + (size_t)cur * D + lane * 4;
      unsafeAtomicAdd(p + 0, a0);
      unsafeAtomicAdd(p + 1, a1);
      unsafeAtomicAdd(p + 2, a2);
      unsafeAtomicAdd(p + 3, a3);
      if (lane == 0) unsafeAtomicAdd(counts + cur, (float)runlen);
      a0 = a1 = a2 = a3 = 0.f;
      cur = g;
      runlen = 0;
    }
    const uint2 v = Hv[(size_t)n * 32 + lane];
    a0 += b2f(v.x << 16);
    a1 += b2f(v.x & 0xffff0000u);
    a2 += b2f(v.y << 16);
    a3 += b2f(v.y & 0xffff0000u);
    ++runlen;
  }
  float* p = sums + (size_t)cur * D + lane * 4;
  unsafeAtomicAdd(p + 0, a0);
  unsafeAtomicAdd(p + 1, a1);
  unsafeAtomicAdd(p + 2, a2);
  unsafeAtomicAdd(p + 3, a3);
  if (lane == 0) unsafeAtomicAdd(counts + cur, (float)runlen);
}

__global__ __launch_bounds__(256) void pool_norm_kernel(
    float* __restrict__ out, const float* __restrict__ counts, int n) {
  int i = blockIdx.x * 256 + threadIdx.x;
  if (i >= n) return;
  float cnt = counts[i / D];
  out[i] = out[i] / fmaxf(cnt, 1.0f);
}

// ---------------------------------------------------------------------------
extern "C" void kernel_launch(void* const* d_in, const int* in_sizes, int n_in,
                              void* d_out, int out_size, void* d_ws,
                              size_t ws_size, hipStream_t stream) {
  const float* x = (const float*)d_in[0];
  const int* ei = (const int*)d_in[1];
  const int* batch = (const int*)d_in[2];
  const float* B[6] = {(const float*)d_in[4],  (const float*)d_in[6],
                       (const float*)d_in[8],  (const float*)d_in[10],
                       (const float*)d_in[12], (const float*)d_in[14]};

  const int n_nodes = in_sizes[2];
  const int n_edges = in_sizes[1] / 2;
  const int n_graphs = out_size / D;
  const int* src = ei;
  const int* dst = ei + n_edges;

  const size_t matB = (size_t)n_nodes * D * sizeof(unsigned short);  // 25.6 MB
  unsigned short* bufA = (unsigned short*)d_ws;
  unsigned short* bufB = (unsigned short*)((char*)d_ws + matB);
  unsigned short* bufC = (unsigned short*)((char*)d_ws + 2 * matB);
  unsigned short* wpack = (unsigned short*)((char*)d_ws + 3 * matB);
  int* rowptr = (int*)((char*)wpack + 6 * 16384 * sizeof(unsigned short));
  int* cnt = rowptr + (n_nodes + 1);
  int* colidx = cnt + n_nodes;
  unsigned short* rank = (unsigned short*)(colidx + n_edges);
  int* chunkSums = (int*)(rank + n_edges);
  float* counts = (float*)(chunkSums + 256);

  const dim3 blk(256);
  const int edge_blocks = (n_edges + 255) / 256;
  const int n_chunks = (n_nodes + SCAN_CHUNK - 1) / SCAN_CHUNK;
  const int gather_blocks = (int)(((long long)n_nodes * 16 + 255) / 256);
  const int pool_groups =
      (n_nodes + POOL_NODES_PER_GROUP - 1) / POOL_NODES_PER_GROUP;
  const int pool_blocks = (pool_groups * 32 + 255) / 256;
  const int n_strips = n_nodes / 32;  // 100000 % 32 == 0
  const int mlp_grid = (n_strips + 7) / 8;  // 1 strip per wave, 8 waves/block
  const int npart = (n_nodes + 7) / 8;
  const int fill_blocks = ((n_edges + FILL_EPB - 1) / FILL_EPB) * 8;

  // ---- precompute: convert x, pack weights, build CSR ----
  convert_kernel<<<(n_nodes * (D / 8) + 255) / 256, blk, 0, stream>>>(
      x, bufA, n_nodes * (D / 8));
  pack_w6_kernel<<<48, blk, 0, stream>>>(
      (const float*)d_in[3], (const float*)d_in[5], (const float*)d_in[7],
      (const float*)d_in[9], (const float*)d_in[11], (const float*)d_in[13],
      wpack);

  hipMemsetAsync(cnt, 0, (size_t)n_nodes * sizeof(int), stream);
  hist_kernel<<<edge_blocks, blk, 0, stream>>>(dst, cnt, rank, n_edges);
  scanA_kernel<<<n_chunks, blk, 0, stream>>>(cnt, rowptr, chunkSums, n_nodes);
  scanB_kernel<<<1, blk, 0, stream>>>(chunkSums, n_chunks);
  scanC_kernel<<<(n_nodes + 256) / 256, blk, 0, stream>>>(rowptr, chunkSums,
                                                          n_nodes, n_edges);
  fill_kernel<<<fill_blocks, blk, 0, stream>>>(src, dst, rank, rowptr, colidx,
                                               n_edges, npart);

  // ---- layer 1 ----
  gather_bf16_kernel<<<gather_blocks, blk, 0, stream>>>(bufA, rowptr, colidx,
                                                        bufB, n_nodes);
  mlp2_kernel<1><<<mlp_grid, 512, 0, stream>>>(bufB, wpack + 0 * 16384,
                                               wpack + 1 * 16384, B[0], B[1],
                                               bufC, n_strips);
  // ---- layer 2 ----
  gather_bf16_kernel<<<gather_blocks, blk, 0, stream>>>(bufC, rowptr, colidx,
                                                        bufB, n_nodes);
  mlp2_kernel<1><<<mlp_grid, 512, 0, stream>>>(bufB, wpack + 2 * 16384,
                                               wpack + 3 * 16384, B[2], B[3],
                                               bufA, n_strips);
  // ---- layer 3 ----
  gather_bf16_kernel<<<gather_blocks, blk, 0, stream>>>(bufA, rowptr, colidx,
                                                        bufB, n_nodes);
  mlp2_kernel<0><<<mlp_grid, 512, 0, stream>>>(bufB, wpack + 4 * 16384,
                                               wpack + 5 * 16384, B[4], B[5],
                                               bufC, n_strips);

  // ---- global mean pool ----
  hipMemsetAsync(d_out, 0, (size_t)out_size * sizeof(float), stream);
  hipMemsetAsync(counts, 0, (size_t)n_graphs * sizeof(float), stream);
  pool_kernel<<<pool_blocks, blk, 0, stream>>>(bufC, batch, (float*)d_out,
                                               counts, n_nodes);
  pool_norm_kernel<<<(out_size + 255) / 256, blk, 0, stream>>>((float*)d_out,
                                                               counts,
                                                               out_size);
}

// Round 8
// 358.940 us; speedup vs baseline: 1.5175x; 1.1907x over previous
//
#include <hip/hip_runtime.h>

#define D 128
#define NB_E 512  // edge-slice blocks for bucket count/scatter

typedef __attribute__((ext_vector_type(8))) short bf16x8;
typedef __attribute__((ext_vector_type(16))) float f32x16;

__device__ inline float b2f(unsigned int hi16_as_lo) {
  union { unsigned int u; float f; } v;
  v.u = hi16_as_lo;
  return v.f;
}
__device__ inline unsigned short f2b(float f) {  // RNE f32 -> bf16
  union { float f; unsigned int u; } v;
  v.f = f;
  unsigned int r = v.u + 0x7FFFu + ((v.u >> 16) & 1u);
  return (unsigned short)(r >> 16);
}
__device__ inline unsigned int pk2(float lo, float hi) {
  return (unsigned int)f2b(lo) | ((unsigned int)f2b(hi) << 16);
}

// ---------------------------------------------------------------------------
// f32 -> bf16 convert (8 elems/thread)
// ---------------------------------------------------------------------------
__global__ __launch_bounds__(256) void convert_kernel(
    const float* __restrict__ in, unsigned short* __restrict__ out, int n8) {
  int i = blockIdx.x * 256 + threadIdx.x;
  if (i >= n8) return;
  const float4 a = *reinterpret_cast<const float4*>(in + (size_t)i * 8);
  const float4 b = *reinterpret_cast<const float4*>(in + (size_t)i * 8 + 4);
  unsigned short o[8] = {f2b(a.x), f2b(a.y), f2b(a.z), f2b(a.w),
                         f2b(b.x), f2b(b.y), f2b(b.z), f2b(b.w)};
  *reinterpret_cast<bf16x8*>(out + (size_t)i * 8) =
      *reinterpret_cast<bf16x8*>(o);
}

// ---------------------------------------------------------------------------
// Pack all 6 W into MFMA fragment order.
// ---------------------------------------------------------------------------
__global__ __launch_bounds__(256) void pack_w6_kernel(
    const float* __restrict__ w0, const float* __restrict__ w1,
    const float* __restrict__ w2, const float* __restrict__ w3,
    const float* __restrict__ w4, const float* __restrict__ w5,
    unsigned short* __restrict__ Wp) {
  const int m = blockIdx.x >> 3;
  const float* W = m == 0 ? w0
                 : m == 1 ? w1
                 : m == 2 ? w2
                 : m == 3 ? w3
                 : m == 4 ? w4
                          : w5;
  const int idx = (blockIdx.x & 7) * 256 + threadIdx.x;  // 0..2047
  const int l = idx & 63;
  const int s = (idx >> 6) & 7;
  const int t = idx >> 9;
  const int n = (t << 5) + (l & 31);
  const int k0 = (s << 4) + ((l >> 5) << 3);
  unsigned short o[8];
#pragma unroll
  for (int i = 0; i < 8; ++i) o[i] = f2b(W[(size_t)(k0 + i) * D + n]);
  *reinterpret_cast<bf16x8*>(Wp + (size_t)m * 16384 + (size_t)idx * 8) =
      *reinterpret_cast<bf16x8*>(o);
}

// ---------------------------------------------------------------------------
// Atomic-free CSR build via two-level counting sort (LDS atomics only).
// Buckets of 256 nodes; NBU = ceil(n_nodes/256) <= 512.
// ---------------------------------------------------------------------------
__global__ __launch_bounds__(256) void bktA_kernel(
    const int* __restrict__ dst, int* __restrict__ bcount, int n_edges,
    int NBU, int epb) {
  __shared__ int cnt[512];
  for (int i = threadIdx.x; i < NBU; i += 256) cnt[i] = 0;
  __syncthreads();
  const int e0 = blockIdx.x * epb;
  const int e1 = min(e0 + epb, n_edges);
  for (int e = e0 + threadIdx.x; e < e1; e += 256)
    atomicAdd(&cnt[dst[e] >> 8], 1);
  __syncthreads();
  int* out = bcount + (size_t)blockIdx.x * NBU;
  for (int i = threadIdx.x; i < NBU; i += 256) out[i] = cnt[i];
}

// Per bucket j: exclusive scan of bcount[b][j] over b=0..NB_E-1.
__global__ __launch_bounds__(256) void bktB_kernel(
    const int* __restrict__ bcount, int* __restrict__ boff,
    int* __restrict__ btot, int NBU) {
  __shared__ int lds[256];
  const int j = blockIdx.x;
  const int t = threadIdx.x;
  const int a = bcount[(size_t)(2 * t) * NBU + j];
  const int b = bcount[(size_t)(2 * t + 1) * NBU + j];
  const int s = a + b;
  lds[t] = s;
  __syncthreads();
#pragma unroll
  for (int off = 1; off < 256; off <<= 1) {
    int p = 0;
    if (t >= off) p = lds[t - off];
    __syncthreads();
    lds[t] += p;
    __syncthreads();
  }
  const int excl = lds[t] - s;
  boff[(size_t)(2 * t) * NBU + j] = excl;
  boff[(size_t)(2 * t + 1) * NBU + j] = excl + a;
  if (t == 255) btot[j] = lds[255];
}

// Exclusive scan of btot (NBU <= 511) -> base[0..NBU] (base[NBU] = n_edges).
__global__ __launch_bounds__(256) void bktBase_kernel(
    const int* __restrict__ btot, int* __restrict__ base, int NBU) {
  __shared__ int lds[256];
  const int t = threadIdx.x;
  const int a = (2 * t < NBU) ? btot[2 * t] : 0;
  const int b = (2 * t + 1 < NBU) ? btot[2 * t + 1] : 0;
  const int s = a + b;
  lds[t] = s;
  __syncthreads();
#pragma unroll
  for (int off = 1; off < 256; off <<= 1) {
    int p = 0;
    if (t >= off) p = lds[t - off];
    __syncthreads();
    lds[t] += p;
    __syncthreads();
  }
  const int excl = lds[t] - s;
  if (2 * t <= NBU) base[2 * t] = excl;
  if (2 * t + 1 <= NBU) base[2 * t + 1] = excl + a;
}

// Scatter edges into bucket-grouped ebuf: (dstLocal<<17)|src (src < 2^17).
__global__ __launch_bounds__(256) void bktC_kernel(
    const int* __restrict__ src, const int* __restrict__ dst,
    const int* __restrict__ boff, const int* __restrict__ base,
    unsigned int* __restrict__ ebuf, int n_edges, int NBU, int epb) {
  __shared__ int cur[512];
  const int* bo = boff + (size_t)blockIdx.x * NBU;
  for (int i = threadIdx.x; i < NBU; i += 256) cur[i] = base[i] + bo[i];
  __syncthreads();
  const int e0 = blockIdx.x * epb;
  const int e1 = min(e0 + epb, n_edges);
  for (int e = e0 + threadIdx.x; e < e1; e += 256) {
    const int d = dst[e];
    const int pos = atomicAdd(&cur[d >> 8], 1);
    ebuf[pos] = ((unsigned int)(d & 255) << 17) | (unsigned int)src[e];
  }
}

// Per bucket: LDS hist(256) -> scan -> rowptr + LDS-cursor fill of col.
__global__ __launch_bounds__(256) void bktD_kernel(
    const unsigned int* __restrict__ ebuf, const int* __restrict__ base,
    int* __restrict__ rowptr, int* __restrict__ col, int n_nodes) {
  __shared__ int hist[256];
  __shared__ int lds[256];
  __shared__ int cursor[256];
  const int j = blockIdx.x;
  const int t = threadIdx.x;
  hist[t] = 0;
  __syncthreads();
  const int e0 = base[j], e1 = base[j + 1];
  for (int e = e0 + t; e < e1; e += 256)
    atomicAdd(&hist[ebuf[e] >> 17], 1);
  __syncthreads();
  const int h = hist[t];
  lds[t] = h;
  __syncthreads();
#pragma unroll
  for (int off = 1; off < 256; off <<= 1) {
    int p = 0;
    if (t >= off) p = lds[t - off];
    __syncthreads();
    lds[t] += p;
    __syncthreads();
  }
  const int excl = lds[t] - h;
  const int node = (j << 8) + t;
  if (node <= n_nodes) rowptr[node] = e0 + excl;  // t=160@last bucket -> sentinel
  cursor[t] = e0 + excl;
  __syncthreads();
  for (int e = e0 + t; e < e1; e += 256) {
    const unsigned int v = ebuf[e];
    const int pos = atomicAdd(&cursor[v >> 17], 1);
    col[pos] = (int)(v & 0x1FFFFu);
  }
}

// ---------------------------------------------------------------------------
// Gather aggregation (bf16): out[n] = X[n] + sum_{j} X[col[j]]
// 16 lanes/node, 16 B (uint4) per lane; unrolled x4.
// ---------------------------------------------------------------------------
__global__ __launch_bounds__(256) void gather_bf16_kernel(
    const unsigned short* __restrict__ X, const int* __restrict__ rowptr,
    const int* __restrict__ col, unsigned short* __restrict__ out,
    int n_nodes) {
  const int t = blockIdx.x * 256 + threadIdx.x;
  const int g = t >> 4;
  if (g >= n_nodes) return;
  const int c = t & 15;
  const uint4* Xv = reinterpret_cast<const uint4*>(X);
  const uint4 u = Xv[(size_t)g * 16 + c];  // self term
  float a0 = b2f(u.x << 16), a1 = b2f(u.x & 0xffff0000u);
  float a2 = b2f(u.y << 16), a3 = b2f(u.y & 0xffff0000u);
  float a4 = b2f(u.z << 16), a5 = b2f(u.z & 0xffff0000u);
  float a6 = b2f(u.w << 16), a7 = b2f(u.w & 0xffff0000u);
  const int beg = rowptr[g], end = rowptr[g + 1];
  int j = beg;
  for (; j + 4 <= end; j += 4) {
    const int s0 = col[j + 0];
    const int s1 = col[j + 1];
    const int s2 = col[j + 2];
    const int s3 = col[j + 3];
    const uint4 w0 = Xv[(size_t)s0 * 16 + c];
    const uint4 w1 = Xv[(size_t)s1 * 16 + c];
    const uint4 w2 = Xv[(size_t)s2 * 16 + c];
    const uint4 w3 = Xv[(size_t)s3 * 16 + c];
    a0 += b2f(w0.x << 16); a1 += b2f(w0.x & 0xffff0000u);
    a2 += b2f(w0.y << 16); a3 += b2f(w0.y & 0xffff0000u);
    a4 += b2f(w0.z << 16); a5 += b2f(w0.z & 0xffff0000u);
    a6 += b2f(w0.w << 16); a7 += b2f(w0.w & 0xffff0000u);
    a0 += b2f(w1.x << 16); a1 += b2f(w1.x & 0xffff0000u);
    a2 += b2f(w1.y << 16); a3 += b2f(w1.y & 0xffff0000u);
    a4 += b2f(w1.z << 16); a5 += b2f(w1.z & 0xffff0000u);
    a6 += b2f(w1.w << 16); a7 += b2f(w1.w & 0xffff0000u);
    a0 += b2f(w2.x << 16); a1 += b2f(w2.x & 0xffff0000u);
    a2 += b2f(w2.y << 16); a3 += b2f(w2.y & 0xffff0000u);
    a4 += b2f(w2.z << 16); a5 += b2f(w2.z & 0xffff0000u);
    a6 += b2f(w2.w << 16); a7 += b2f(w2.w & 0xffff0000u);
    a0 += b2f(w3.x << 16); a1 += b2f(w3.x & 0xffff0000u);
    a2 += b2f(w3.y << 16); a3 += b2f(w3.y & 0xffff0000u);
    a4 += b2f(w3.z << 16); a5 += b2f(w3.z & 0xffff0000u);
    a6 += b2f(w3.w << 16); a7 += b2f(w3.w & 0xffff0000u);
  }
  for (; j < end; ++j) {
    const uint4 w = Xv[(size_t)col[j] * 16 + c];
    a0 += b2f(w.x << 16); a1 += b2f(w.x & 0xffff0000u);
    a2 += b2f(w.y << 16); a3 += b2f(w.y & 0xffff0000u);
    a4 += b2f(w.z << 16); a5 += b2f(w.z & 0xffff0000u);
    a6 += b2f(w.w << 16); a7 += b2f(w.w & 0xffff0000u);
  }
  uint4 o;
  o.x = pk2(a0, a1);
  o.y = pk2(a2, a3);
  o.z = pk2(a4, a5);
  o.w = pk2(a6, a7);
  reinterpret_cast<uint4*>(out)[(size_t)g * 16 + c] = o;
}

// ---------------------------------------------------------------------------
// Fused MLP pair: out = [relu]( relu(S@W1+b1) @ W2 + b2 ), bf16 io, f32 acc.
// 512-thread blocks (8 waves), each wave owns one 32-row strip.
// ---------------------------------------------------------------------------
template <int RELU>
__global__ __launch_bounds__(512) void mlp2_kernel(
    const unsigned short* __restrict__ X, const unsigned short* __restrict__ Wp1,
    const unsigned short* __restrict__ Wp2, const float* __restrict__ bias1,
    const float* __restrict__ bias2, unsigned short* __restrict__ out,
    int n_strips) {
  __shared__ unsigned short wl1[16384];  // 32 KB
  __shared__ unsigned short wl2[16384];  // 32 KB
  __shared__ float bl1[128], bl2[128];

  const int lx = threadIdx.x & 63;
  const int wid = threadIdx.x >> 6;
  const int strip = blockIdx.x * 8 + wid;
  const int h = lx >> 5;
  const int nl = lx & 31;

  bf16x8 xf[8];
  if (strip < n_strips) {
    const unsigned short* xrow = X + (size_t)(strip * 32 + nl) * D + h * 8;
#pragma unroll
    for (int s = 0; s < 8; ++s)
      xf[s] = *reinterpret_cast<const bf16x8*>(xrow + s * 16);
  }

  for (int i = threadIdx.x * 8; i < 16384; i += 512 * 8) {
    *reinterpret_cast<bf16x8*>(wl1 + i) = *reinterpret_cast<const bf16x8*>(Wp1 + i);
    *reinterpret_cast<bf16x8*>(wl2 + i) = *reinterpret_cast<const bf16x8*>(Wp2 + i);
  }
  if (threadIdx.x < 128) {
    bl1[threadIdx.x] = bias1[threadIdx.x];
    bl2[threadIdx.x] = bias2[threadIdx.x];
  }
  __syncthreads();
  if (strip >= n_strips) return;

  f32x16 acc1[4];
#pragma unroll
  for (int t1 = 0; t1 < 4; ++t1)
#pragma unroll
    for (int r = 0; r < 16; ++r)
      acc1[t1][r] = bl1[32 * t1 + (r & 3) + 8 * (r >> 2) + 4 * h];
#pragma unroll
  for (int s = 0; s < 8; ++s) {
#pragma unroll
    for (int t1 = 0; t1 < 4; ++t1) {
      const bf16x8 wf = *reinterpret_cast<const bf16x8*>(
          wl1 + ((t1 * 8 + s) * 64 + lx) * 8);
      acc1[t1] =
          __builtin_amdgcn_mfma_f32_32x32x16_bf16(wf, xf[s], acc1[t1], 0, 0, 0);
    }
  }

  f32x16 acc2[4];
#pragma unroll
  for (int t = 0; t < 4; ++t)
#pragma unroll
    for (int r = 0; r < 16; ++r)
      acc2[t][r] = bl2[32 * t + (r & 3) + 8 * (r >> 2) + 4 * h];
#pragma unroll
  for (int s2 = 0; s2 < 8; ++s2) {
    const int t1 = s2 >> 1;
    const int ro = (s2 & 1) << 3;
    const float g0 = fmaxf(acc1[t1][ro + 0], 0.f);
    const float g1 = fmaxf(acc1[t1][ro + 1], 0.f);
    const float g2 = fmaxf(acc1[t1][ro + 2], 0.f);
    const float g3 = fmaxf(acc1[t1][ro + 3], 0.f);
    const float g4 = fmaxf(acc1[t1][ro + 4], 0.f);
    const float g5 = fmaxf(acc1[t1][ro + 5], 0.f);
    const float g6 = fmaxf(acc1[t1][ro + 6], 0.f);
    const float g7 = fmaxf(acc1[t1][ro + 7], 0.f);
    const unsigned int pA0 = pk2(g0, g1), pA1 = pk2(g2, g3);
    const unsigned int pB0 = pk2(g4, g5), pB1 = pk2(g6, g7);
    const unsigned int sA0 = (unsigned int)__shfl((int)pA0, lx ^ 32, 64);
    const unsigned int sA1 = (unsigned int)__shfl((int)pA1, lx ^ 32, 64);
    const unsigned int sB0 = (unsigned int)__shfl((int)pB0, lx ^ 32, 64);
    const unsigned int sB1 = (unsigned int)__shfl((int)pB1, lx ^ 32, 64);
    union { unsigned int u[4]; bf16x8 v; } fr;
    fr.u[0] = h ? sB0 : pA0;
    fr.u[1] = h ? sB1 : pA1;
    fr.u[2] = h ? pB0 : sA0;
    fr.u[3] = h ? pB1 : sA1;
#pragma unroll
    for (int t = 0; t < 4; ++t) {
      const bf16x8 wf = *reinterpret_cast<const bf16x8*>(
          wl2 + ((t * 8 + s2) * 64 + lx) * 8);
      acc2[t] =
          __builtin_amdgcn_mfma_f32_32x32x16_bf16(wf, fr.v, acc2[t], 0, 0, 0);
    }
  }

  unsigned short* orow = out + (size_t)(strip * 32 + nl) * D + h * 8;
#pragma unroll
  for (int s = 0; s < 8; ++s) {
    const int t = s >> 1;
    const int ro = (s & 1) << 3;
    float g0 = acc2[t][ro + 0], g1 = acc2[t][ro + 1];
    float g2 = acc2[t][ro + 2], g3 = acc2[t][ro + 3];
    float g4 = acc2[t][ro + 4], g5 = acc2[t][ro + 5];
    float g6 = acc2[t][ro + 6], g7 = acc2[t][ro + 7];
    if (RELU) {
      g0 = fmaxf(g0, 0.f); g1 = fmaxf(g1, 0.f);
      g2 = fmaxf(g2, 0.f); g3 = fmaxf(g3, 0.f);
      g4 = fmaxf(g4, 0.f); g5 = fmaxf(g5, 0.f);
      g6 = fmaxf(g6, 0.f); g7 = fmaxf(g7, 0.f);
    }
    const unsigned int pA0 = pk2(g0, g1), pA1 = pk2(g2, g3);
    const unsigned int pB0 = pk2(g4, g5), pB1 = pk2(g6, g7);
    const unsigned int sA0 = (unsigned int)__shfl((int)pA0, lx ^ 32, 64);
    const unsigned int sA1 = (unsigned int)__shfl((int)pA1, lx ^ 32, 64);
    const unsigned int sB0 = (unsigned int)__shfl((int)pB0, lx ^ 32, 64);
    const unsigned int sB1 = (unsigned int)__shfl((int)pB1, lx ^ 32, 64);
    union { unsigned int u[4]; bf16x8 v; } fr;
    fr.u[0] = h ? sB0 : pA0;
    fr.u[1] = h ? sB1 : pA1;
    fr.u[2] = h ? pB0 : sA0;
    fr.u[3] = h ? pB1 : sA1;
    *reinterpret_cast<bf16x8*>(orow + s * 16) = fr.v;
  }
}

// ---------------------------------------------------------------------------
// Global mean pool (batch sorted): run-length accumulate, atomic flush per run.
// ---------------------------------------------------------------------------
#define POOL_NODES_PER_GROUP 128

__global__ __launch_bounds__(256) void pool_kernel(
    const unsigned short* __restrict__ H, const int* __restrict__ batch,
    float* __restrict__ sums, float* __restrict__ counts, int n_nodes) {
  const int group = (blockIdx.x * 256 + threadIdx.x) >> 5;
  const int lane = threadIdx.x & 31;
  const int n0 = group * POOL_NODES_PER_GROUP;
  if (n0 >= n_nodes) return;
  const int n1 = min(n0 + POOL_NODES_PER_GROUP, n_nodes);
  const uint2* Hv = reinterpret_cast<const uint2*>(H);

  float a0 = 0.f, a1 = 0.f, a2 = 0.f, a3 = 0.f;
  int cur = batch[n0];
  int runlen = 0;
  for (int n = n0; n < n1; ++n) {
    const int g = batch[n];
    if (g != cur) {
      float* p = sums + (size_t)cur * D + lane * 4;
      unsafeAtomicAdd(p + 0, a0);
      unsafeAtomicAdd(p + 1, a1);
      unsafeAtomicAdd(p + 2, a2);
      unsafeAtomicAdd(p + 3, a3);
      if (lane == 0) unsafeAtomicAdd(counts + cur, (float)runlen);
      a0 = a1 = a2 = a3 = 0.f;
      cur = g;
      runlen = 0;
    }
    const uint2 v = Hv[(size_t)n * 32 + lane];
    a0 += b2f(v.x << 16);
    a1 += b2f(v.x & 0xffff0000u);
    a2 += b2f(v.y << 16);
    a3 += b2f(v.y & 0xffff0000u);
    ++runlen;
  }
  float* p = sums + (size_t)cur * D + lane * 4;
  unsafeAtomicAdd(p + 0, a0);
  unsafeAtomicAdd(p + 1, a1);
  unsafeAtomicAdd(p + 2, a2);
  unsafeAtomicAdd(p + 3, a3);
  if (lane == 0) unsafeAtomicAdd(counts + cur, (float)runlen);
}

__global__ __launch_bounds__(256) void pool_norm_kernel(
    float* __restrict__ out, const float* __restrict__ counts, int n) {
  int i = blockIdx.x * 256 + threadIdx.x;
  if (i >= n) return;
  float cnt = counts[i / D];
  out[i] = out[i] / fmaxf(cnt, 1.0f);
}

// ---------------------------------------------------------------------------
extern "C" void kernel_launch(void* const* d_in, const int* in_sizes, int n_in,
                              void* d_out, int out_size, void* d_ws,
                              size_t ws_size, hipStream_t stream) {
  const float* x = (const float*)d_in[0];
  const int* ei = (const int*)d_in[1];
  const int* batch = (const int*)d_in[2];
  const float* B[6] = {(const float*)d_in[4],  (const float*)d_in[6],
                       (const float*)d_in[8],  (const float*)d_in[10],
                       (const float*)d_in[12], (const float*)d_in[14]};

  const int n_nodes = in_sizes[2];
  const int n_edges = in_sizes[1] / 2;
  const int n_graphs = out_size / D;
  const int* src = ei;
  const int* dst = ei + n_edges;

  const size_t matB = (size_t)n_nodes * D * sizeof(unsigned short);  // 25.6 MB
  unsigned short* bufA = (unsigned short*)d_ws;
  unsigned short* bufB = (unsigned short*)((char*)d_ws + matB);
  unsigned short* bufC = (unsigned short*)((char*)d_ws + 2 * matB);
  unsigned short* wpack = (unsigned short*)((char*)d_ws + 3 * matB);
  int* rowptr = (int*)((char*)wpack + 6 * 16384 * sizeof(unsigned short));
  int* colidx = rowptr + (n_nodes + 1);
  unsigned int* ebuf = (unsigned int*)(colidx + n_edges);
  const int NBU = (n_nodes + 255) >> 8;  // 391
  int* bcount = (int*)(ebuf + n_edges);
  int* boff = bcount + (size_t)NB_E * NBU;
  int* btot = boff + (size_t)NB_E * NBU;
  int* base = btot + NBU;
  float* counts = (float*)(base + NBU + 2);

  const dim3 blk(256);
  const int gather_blocks = (int)(((long long)n_nodes * 16 + 255) / 256);
  const int pool_groups =
      (n_nodes + POOL_NODES_PER_GROUP - 1) / POOL_NODES_PER_GROUP;
  const int pool_blocks = (pool_groups * 32 + 255) / 256;
  const int n_strips = n_nodes / 32;        // 100000 % 32 == 0
  const int mlp_grid = (n_strips + 7) / 8;  // 1 strip per wave
  const int epb = (n_edges + NB_E - 1) / NB_E;

  // ---- precompute: convert x, pack weights, counting-sort CSR ----
  convert_kernel<<<(n_nodes * (D / 8) + 255) / 256, blk, 0, stream>>>(
      x, bufA, n_nodes * (D / 8));
  pack_w6_kernel<<<48, blk, 0, stream>>>(
      (const float*)d_in[3], (const float*)d_in[5], (const float*)d_in[7],
      (const float*)d_in[9], (const float*)d_in[11], (const float*)d_in[13],
      wpack);

  bktA_kernel<<<NB_E, blk, 0, stream>>>(dst, bcount, n_edges, NBU, epb);
  bktB_kernel<<<NBU, blk, 0, stream>>>(bcount, boff, btot, NBU);
  bktBase_kernel<<<1, blk, 0, stream>>>(btot, base, NBU);
  bktC_kernel<<<NB_E, blk, 0, stream>>>(src, dst, boff, base, ebuf, n_edges,
                                        NBU, epb);
  bktD_kernel<<<NBU, blk, 0, stream>>>(ebuf, base, rowptr, colidx, n_nodes);

  // ---- layer 1 ----
  gather_bf16_kernel<<<gather_blocks, blk, 0, stream>>>(bufA, rowptr, colidx,
                                                        bufB, n_nodes);
  mlp2_kernel<1><<<mlp_grid, 512, 0, stream>>>(bufB, wpack + 0 * 16384,
                                               wpack + 1 * 16384, B[0], B[1],
                                               bufC, n_strips);
  // ---- layer 2 ----
  gather_bf16_kernel<<<gather_blocks, blk, 0, stream>>>(bufC, rowptr, colidx,
                                                        bufB, n_nodes);
  mlp2_kernel<1><<<mlp_grid, 512, 0, stream>>>(bufB, wpack + 2 * 16384,
                                               wpack + 3 * 16384, B[2], B[3],
                                               bufA, n_strips);
  // ---- layer 3 ----
  gather_bf16_kernel<<<gather_blocks, blk, 0, stream>>>(bufA, rowptr, colidx,
                                                        bufB, n_nodes);
  mlp2_kernel<0><<<mlp_grid, 512, 0, stream>>>(bufB, wpack + 4 * 16384,
                                               wpack + 5 * 16384, B[4], B[5],
                                               bufC, n_strips);

  // ---- global mean pool ----
  hipMemsetAsync(d_out, 0, (size_t)out_size * sizeof(float), stream);
  hipMemsetAsync(counts, 0, (size_t)n_graphs * sizeof(float), stream);
  pool_kernel<<<pool_blocks, blk, 0, stream>>>(bufC, batch, (float*)d_out,
                                               counts, n_nodes);
  pool_norm_kernel<<<(out_size + 255) / 256, blk, 0, stream>>>((float*)d_out,
                                                               counts,
                                                               out_size);
}

// Round 11
// 356.982 us; speedup vs baseline: 1.5259x; 1.0055x over previous
//
#include <hip/hip_runtime.h>

#define D 128
#define NB_E 512  // edge-slice blocks for bucket count/scatter

typedef __attribute__((ext_vector_type(8))) short bf16x8;
typedef __attribute__((ext_vector_type(16))) float f32x16;

__device__ inline float b2f(unsigned int hi16_as_lo) {
  union { unsigned int u; float f; } v;
  v.u = hi16_as_lo;
  return v.f;
}
__device__ inline unsigned short f2b(float f) {  // RNE f32 -> bf16
  union { float f; unsigned int u; } v;
  v.f = f;
  unsigned int r = v.u + 0x7FFFu + ((v.u >> 16) & 1u);
  return (unsigned short)(r >> 16);
}
__device__ inline unsigned int pk2(float lo, float hi) {
  return (unsigned int)f2b(lo) | ((unsigned int)f2b(hi) << 16);
}

// ---------------------------------------------------------------------------
// f32 -> bf16 convert (8 elems/thread)
// ---------------------------------------------------------------------------
__global__ __launch_bounds__(256) void convert_kernel(
    const float* __restrict__ in, unsigned short* __restrict__ out, int n8) {
  int i = blockIdx.x * 256 + threadIdx.x;
  if (i >= n8) return;
  const float4 a = *reinterpret_cast<const float4*>(in + (size_t)i * 8);
  const float4 b = *reinterpret_cast<const float4*>(in + (size_t)i * 8 + 4);
  unsigned short o[8] = {f2b(a.x), f2b(a.y), f2b(a.z), f2b(a.w),
                         f2b(b.x), f2b(b.y), f2b(b.z), f2b(b.w)};
  *reinterpret_cast<bf16x8*>(out + (size_t)i * 8) =
      *reinterpret_cast<bf16x8*>(o);
}

// ---------------------------------------------------------------------------
// Pack all 6 W into MFMA fragment order.
// ---------------------------------------------------------------------------
__global__ __launch_bounds__(256) void pack_w6_kernel(
    const float* __restrict__ w0, const float* __restrict__ w1,
    const float* __restrict__ w2, const float* __restrict__ w3,
    const float* __restrict__ w4, const float* __restrict__ w5,
    unsigned short* __restrict__ Wp) {
  const int m = blockIdx.x >> 3;
  const float* W = m == 0 ? w0
                 : m == 1 ? w1
                 : m == 2 ? w2
                 : m == 3 ? w3
                 : m == 4 ? w4
                          : w5;
  const int idx = (blockIdx.x & 7) * 256 + threadIdx.x;  // 0..2047
  const int l = idx & 63;
  const int s = (idx >> 6) & 7;
  const int t = idx >> 9;
  const int n = (t << 5) + (l & 31);
  const int k0 = (s << 4) + ((l >> 5) << 3);
  unsigned short o[8];
#pragma unroll
  for (int i = 0; i < 8; ++i) o[i] = f2b(W[(size_t)(k0 + i) * D + n]);
  *reinterpret_cast<bf16x8*>(Wp + (size_t)m * 16384 + (size_t)idx * 8) =
      *reinterpret_cast<bf16x8*>(o);
}

// ---------------------------------------------------------------------------
// Atomic-free CSR build via two-level counting sort (LDS atomics only).
// ---------------------------------------------------------------------------
__global__ __launch_bounds__(256) void bktA_kernel(
    const int* __restrict__ dst, int* __restrict__ bcount, int n_edges,
    int NBU, int epb) {
  __shared__ int cnt[512];
  for (int i = threadIdx.x; i < NBU; i += 256) cnt[i] = 0;
  __syncthreads();
  const int e0 = blockIdx.x * epb;
  const int e1 = min(e0 + epb, n_edges);
  for (int e = e0 + threadIdx.x; e < e1; e += 256)
    atomicAdd(&cnt[dst[e] >> 8], 1);
  __syncthreads();
  int* out = bcount + (size_t)blockIdx.x * NBU;
  for (int i = threadIdx.x; i < NBU; i += 256) out[i] = cnt[i];
}

__global__ __launch_bounds__(256) void bktB_kernel(
    const int* __restrict__ bcount, int* __restrict__ boff,
    int* __restrict__ btot, int NBU) {
  __shared__ int lds[256];
  const int j = blockIdx.x;
  const int t = threadIdx.x;
  const int a = bcount[(size_t)(2 * t) * NBU + j];
  const int b = bcount[(size_t)(2 * t + 1) * NBU + j];
  const int s = a + b;
  lds[t] = s;
  __syncthreads();
#pragma unroll
  for (int off = 1; off < 256; off <<= 1) {
    int p = 0;
    if (t >= off) p = lds[t - off];
    __syncthreads();
    lds[t] += p;
    __syncthreads();
  }
  const int excl = lds[t] - s;
  boff[(size_t)(2 * t) * NBU + j] = excl;
  boff[(size_t)(2 * t + 1) * NBU + j] = excl + a;
  if (t == 255) btot[j] = lds[255];
}

__global__ __launch_bounds__(256) void bktBase_kernel(
    const int* __restrict__ btot, int* __restrict__ base, int NBU) {
  __shared__ int lds[256];
  const int t = threadIdx.x;
  const int a = (2 * t < NBU) ? btot[2 * t] : 0;
  const int b = (2 * t + 1 < NBU) ? btot[2 * t + 1] : 0;
  const int s = a + b;
  lds[t] = s;
  __syncthreads();
#pragma unroll
  for (int off = 1; off < 256; off <<= 1) {
    int p = 0;
    if (t >= off) p = lds[t - off];
    __syncthreads();
    lds[t] += p;
    __syncthreads();
  }
  const int excl = lds[t] - s;
  if (2 * t <= NBU) base[2 * t] = excl;
  if (2 * t + 1 <= NBU) base[2 * t + 1] = excl + a;
}

__global__ __launch_bounds__(256) void bktC_kernel(
    const int* __restrict__ src, const int* __restrict__ dst,
    const int* __restrict__ boff, const int* __restrict__ base,
    unsigned int* __restrict__ ebuf, int n_edges, int NBU, int epb) {
  __shared__ int cur[512];
  const int* bo = boff + (size_t)blockIdx.x * NBU;
  for (int i = threadIdx.x; i < NBU; i += 256) cur[i] = base[i] + bo[i];
  __syncthreads();
  const int e0 = blockIdx.x * epb;
  const int e1 = min(e0 + epb, n_edges);
  for (int e = e0 + threadIdx.x; e < e1; e += 256) {
    const int d = dst[e];
    const int pos = atomicAdd(&cur[d >> 8], 1);
    ebuf[pos] = ((unsigned int)(d & 255) << 17) | (unsigned int)src[e];
  }
}

__global__ __launch_bounds__(256) void bktD_kernel(
    const unsigned int* __restrict__ ebuf, const int* __restrict__ base,
    int* __restrict__ rowptr, int* __restrict__ col, int n_nodes) {
  __shared__ int hist[256];
  __shared__ int lds[256];
  __shared__ int cursor[256];
  const int j = blockIdx.x;
  const int t = threadIdx.x;
  hist[t] = 0;
  __syncthreads();
  const int e0 = base[j], e1 = base[j + 1];
  for (int e = e0 + t; e < e1; e += 256)
    atomicAdd(&hist[ebuf[e] >> 17], 1);
  __syncthreads();
  const int h = hist[t];
  lds[t] = h;
  __syncthreads();
#pragma unroll
  for (int off = 1; off < 256; off <<= 1) {
    int p = 0;
    if (t >= off) p = lds[t - off];
    __syncthreads();
    lds[t] += p;
    __syncthreads();
  }
  const int excl = lds[t] - h;
  const int node = (j << 8) + t;
  if (node <= n_nodes) rowptr[node] = e0 + excl;
  cursor[t] = e0 + excl;
  __syncthreads();
  for (int e = e0 + t; e < e1; e += 256) {
    const unsigned int v = ebuf[e];
    const int pos = atomicAdd(&cursor[v >> 17], 1);
    col[pos] = (int)(v & 0x1FFFFu);
  }
}

// ---------------------------------------------------------------------------
// Gather aggregation (bf16): out[n] = X[n] + sum_{j} X[col[j]]
// 32 lanes/node: 16 feature-lanes (uint4) x 2 edge-slots (stride-2 over the
// edge list) -> halves lockstep-divergence waste; shfl_xor(16) slot reduce.
// ---------------------------------------------------------------------------
__global__ __launch_bounds__(256) void gather_bf16_kernel(
    const unsigned short* __restrict__ X, const int* __restrict__ rowptr,
    const int* __restrict__ col, unsigned short* __restrict__ out,
    int n_nodes) {
  const int t = blockIdx.x * 256 + threadIdx.x;
  const int g = t >> 5;
  if (g >= n_nodes) return;
  const int c = t & 15;           // 16B feature chunk
  const int slot = (t >> 4) & 1;  // edge parity
  const uint4* Xv = reinterpret_cast<const uint4*>(X);
  float a0 = 0.f, a1 = 0.f, a2 = 0.f, a3 = 0.f;
  float a4 = 0.f, a5 = 0.f, a6 = 0.f, a7 = 0.f;
  if (slot == 0) {  // self term
    const uint4 u = Xv[(size_t)g * 16 + c];
    a0 = b2f(u.x << 16); a1 = b2f(u.x & 0xffff0000u);
    a2 = b2f(u.y << 16); a3 = b2f(u.y & 0xffff0000u);
    a4 = b2f(u.z << 16); a5 = b2f(u.z & 0xffff0000u);
    a6 = b2f(u.w << 16); a7 = b2f(u.w & 0xffff0000u);
  }
  const int beg = rowptr[g], end = rowptr[g + 1];
  int j = beg + slot;
  for (; j + 6 < end; j += 8) {  // 4 edges per slot-iteration
    const int s0 = col[j + 0];
    const int s1 = col[j + 2];
    const int s2 = col[j + 4];
    const int s3 = col[j + 6];
    const uint4 w0 = Xv[(size_t)s0 * 16 + c];
    const uint4 w1 = Xv[(size_t)s1 * 16 + c];
    const uint4 w2 = Xv[(size_t)s2 * 16 + c];
    const uint4 w3 = Xv[(size_t)s3 * 16 + c];
    a0 += b2f(w0.x << 16); a1 += b2f(w0.x & 0xffff0000u);
    a2 += b2f(w0.y << 16); a3 += b2f(w0.y & 0xffff0000u);
    a4 += b2f(w0.z << 16); a5 += b2f(w0.z & 0xffff0000u);
    a6 += b2f(w0.w << 16); a7 += b2f(w0.w & 0xffff0000u);
    a0 += b2f(w1.x << 16); a1 += b2f(w1.x & 0xffff0000u);
    a2 += b2f(w1.y << 16); a3 += b2f(w1.y & 0xffff0000u);
    a4 += b2f(w1.z << 16); a5 += b2f(w1.z & 0xffff0000u);
    a6 += b2f(w1.w << 16); a7 += b2f(w1.w & 0xffff0000u);
    a0 += b2f(w2.x << 16); a1 += b2f(w2.x & 0xffff0000u);
    a2 += b2f(w2.y << 16); a3 += b2f(w2.y & 0xffff0000u);
    a4 += b2f(w2.z << 16); a5 += b2f(w2.z & 0xffff0000u);
    a6 += b2f(w2.w << 16); a7 += b2f(w2.w & 0xffff0000u);
    a0 += b2f(w3.x << 16); a1 += b2f(w3.x & 0xffff0000u);
    a2 += b2f(w3.y << 16); a3 += b2f(w3.y & 0xffff0000u);
    a4 += b2f(w3.z << 16); a5 += b2f(w3.z & 0xffff0000u);
    a6 += b2f(w3.w << 16); a7 += b2f(w3.w & 0xffff0000u);
  }
  for (; j < end; j += 2) {
    const uint4 w = Xv[(size_t)col[j] * 16 + c];
    a0 += b2f(w.x << 16); a1 += b2f(w.x & 0xffff0000u);
    a2 += b2f(w.y << 16); a3 += b2f(w.y & 0xffff0000u);
    a4 += b2f(w.z << 16); a5 += b2f(w.z & 0xffff0000u);
    a6 += b2f(w.w << 16); a7 += b2f(w.w & 0xffff0000u);
  }
  // combine the two slots (lanes i <-> i^16 hold the same node)
  a0 += __shfl_xor(a0, 16, 64);
  a1 += __shfl_xor(a1, 16, 64);
  a2 += __shfl_xor(a2, 16, 64);
  a3 += __shfl_xor(a3, 16, 64);
  a4 += __shfl_xor(a4, 16, 64);
  a5 += __shfl_xor(a5, 16, 64);
  a6 += __shfl_xor(a6, 16, 64);
  a7 += __shfl_xor(a7, 16, 64);
  if (slot == 0) {
    uint4 o;
    o.x = pk2(a0, a1);
    o.y = pk2(a2, a3);
    o.z = pk2(a4, a5);
    o.w = pk2(a6, a7);
    reinterpret_cast<uint4*>(out)[(size_t)g * 16 + c] = o;
  }
}

// ---------------------------------------------------------------------------
// Fused MLP pair: out = [relu]( relu(S@W1+b1) @ W2 + b2 ), bf16 io, f32 acc.
// R8-EXACT version (passed at 359 us): pk2 packing + shfl(lx^32) exchange.
// 512-thread blocks (8 waves), each wave owns one 32-row strip.
// ---------------------------------------------------------------------------
template <int RELU>
__global__ __launch_bounds__(512) void mlp2_kernel(
    const unsigned short* __restrict__ X, const unsigned short* __restrict__ Wp1,
    const unsigned short* __restrict__ Wp2, const float* __restrict__ bias1,
    const float* __restrict__ bias2, unsigned short* __restrict__ out,
    int n_strips) {
  __shared__ unsigned short wl1[16384];  // 32 KB
  __shared__ unsigned short wl2[16384];  // 32 KB
  __shared__ float bl1[128], bl2[128];

  const int lx = threadIdx.x & 63;
  const int wid = threadIdx.x >> 6;
  const int strip = blockIdx.x * 8 + wid;
  const int h = lx >> 5;
  const int nl = lx & 31;

  bf16x8 xf[8];
  if (strip < n_strips) {
    const unsigned short* xrow = X + (size_t)(strip * 32 + nl) * D + h * 8;
#pragma unroll
    for (int s = 0; s < 8; ++s)
      xf[s] = *reinterpret_cast<const bf16x8*>(xrow + s * 16);
  }

  for (int i = threadIdx.x * 8; i < 16384; i += 512 * 8) {
    *reinterpret_cast<bf16x8*>(wl1 + i) = *reinterpret_cast<const bf16x8*>(Wp1 + i);
    *reinterpret_cast<bf16x8*>(wl2 + i) = *reinterpret_cast<const bf16x8*>(Wp2 + i);
  }
  if (threadIdx.x < 128) {
    bl1[threadIdx.x] = bias1[threadIdx.x];
    bl2[threadIdx.x] = bias2[threadIdx.x];
  }
  __syncthreads();
  if (strip >= n_strips) return;

  f32x16 acc1[4];
#pragma unroll
  for (int t1 = 0; t1 < 4; ++t1)
#pragma unroll
    for (int r = 0; r < 16; ++r)
      acc1[t1][r] = bl1[32 * t1 + (r & 3) + 8 * (r >> 2) + 4 * h];
#pragma unroll
  for (int s = 0; s < 8; ++s) {
#pragma unroll
    for (int t1 = 0; t1 < 4; ++t1) {
      const bf16x8 wf = *reinterpret_cast<const bf16x8*>(
          wl1 + ((t1 * 8 + s) * 64 + lx) * 8);
      acc1[t1] =
          __builtin_amdgcn_mfma_f32_32x32x16_bf16(wf, xf[s], acc1[t1], 0, 0, 0);
    }
  }

  f32x16 acc2[4];
#pragma unroll
  for (int t = 0; t < 4; ++t)
#pragma unroll
    for (int r = 0; r < 16; ++r)
      acc2[t][r] = bl2[32 * t + (r & 3) + 8 * (r >> 2) + 4 * h];
#pragma unroll
  for (int s2 = 0; s2 < 8; ++s2) {
    const int t1 = s2 >> 1;
    const int ro = (s2 & 1) << 3;
    const float g0 = fmaxf(acc1[t1][ro + 0], 0.f);
    const float g1 = fmaxf(acc1[t1][ro + 1], 0.f);
    const float g2 = fmaxf(acc1[t1][ro + 2], 0.f);
    const float g3 = fmaxf(acc1[t1][ro + 3], 0.f);
    const float g4 = fmaxf(acc1[t1][ro + 4], 0.f);
    const float g5 = fmaxf(acc1[t1][ro + 5], 0.f);
    const float g6 = fmaxf(acc1[t1][ro + 6], 0.f);
    const float g7 = fmaxf(acc1[t1][ro + 7], 0.f);
    const unsigned int pA0 = pk2(g0, g1), pA1 = pk2(g2, g3);
    const unsigned int pB0 = pk2(g4, g5), pB1 = pk2(g6, g7);
    const unsigned int sA0 = (unsigned int)__shfl((int)pA0, lx ^ 32, 64);
    const unsigned int sA1 = (unsigned int)__shfl((int)pA1, lx ^ 32, 64);
    const unsigned int sB0 = (unsigned int)__shfl((int)pB0, lx ^ 32, 64);
    const unsigned int sB1 = (unsigned int)__shfl((int)pB1, lx ^ 32, 64);
    union { unsigned int u[4]; bf16x8 v; } fr;
    fr.u[0] = h ? sB0 : pA0;
    fr.u[1] = h ? sB1 : pA1;
    fr.u[2] = h ? pB0 : sA0;
    fr.u[3] = h ? pB1 : sA1;
#pragma unroll
    for (int t = 0; t < 4; ++t) {
      const bf16x8 wf = *reinterpret_cast<const bf16x8*>(
          wl2 + ((t * 8 + s2) * 64 + lx) * 8);
      acc2[t] =
          __builtin_amdgcn_mfma_f32_32x32x16_bf16(wf, fr.v, acc2[t], 0, 0, 0);
    }
  }

  unsigned short* orow = out + (size_t)(strip * 32 + nl) * D + h * 8;
#pragma unroll
  for (int s = 0; s < 8; ++s) {
    const int t = s >> 1;
    const int ro = (s & 1) << 3;
    float g0 = acc2[t][ro + 0], g1 = acc2[t][ro + 1];
    float g2 = acc2[t][ro + 2], g3 = acc2[t][ro + 3];
    float g4 = acc2[t][ro + 4], g5 = acc2[t][ro + 5];
    float g6 = acc2[t][ro + 6], g7 = acc2[t][ro + 7];
    if (RELU) {
      g0 = fmaxf(g0, 0.f); g1 = fmaxf(g1, 0.f);
      g2 = fmaxf(g2, 0.f); g3 = fmaxf(g3, 0.f);
      g4 = fmaxf(g4, 0.f); g5 = fmaxf(g5, 0.f);
      g6 = fmaxf(g6, 0.f); g7 = fmaxf(g7, 0.f);
    }
    const unsigned int pA0 = pk2(g0, g1), pA1 = pk2(g2, g3);
    const unsigned int pB0 = pk2(g4, g5), pB1 = pk2(g6, g7);
    const unsigned int sA0 = (unsigned int)__shfl((int)pA0, lx ^ 32, 64);
    const unsigned int sA1 = (unsigned int)__shfl((int)pA1, lx ^ 32, 64);
    const unsigned int sB0 = (unsigned int)__shfl((int)pB0, lx ^ 32, 64);
    const unsigned int sB1 = (unsigned int)__shfl((int)pB1, lx ^ 32, 64);
    union { unsigned int u[4]; bf16x8 v; } fr;
    fr.u[0] = h ? sB0 : pA0;
    fr.u[1] = h ? sB1 : pA1;
    fr.u[2] = h ? pB0 : sA0;
    fr.u[3] = h ? pB1 : sA1;
    *reinterpret_cast<bf16x8*>(orow + s * 16) = fr.v;
  }
}

// ---------------------------------------------------------------------------
// Global mean pool (batch sorted): run-length accumulate, atomic flush per run.
// ---------------------------------------------------------------------------
#define POOL_NODES_PER_GROUP 128

__global__ __launch_bounds__(256) void pool_kernel(
    const unsigned short* __restrict__ H, const int* __restrict__ batch,
    float* __restrict__ sums, float* __restrict__ counts, int n_nodes) {
  const int group = (blockIdx.x * 256 + threadIdx.x) >> 5;
  const int lane = threadIdx.x & 31;
  const int n0 = group * POOL_NODES_PER_GROUP;
  if (n0 >= n_nodes) return;
  const int n1 = min(n0 + POOL_NODES_PER_GROUP, n_nodes);
  const uint2* Hv = reinterpret_cast<const uint2*>(H);

  float a0 = 0.f, a1 = 0.f, a2 = 0.f, a3 = 0.f;
  int cur = batch[n0];
  int runlen = 0;
  for (int n = n0; n < n1; ++n) {
    const int g = batch[n];
    if (g != cur) {
      float* p = sums + (size_t)cur * D + lane * 4;
      unsafeAtomicAdd(p + 0, a0);
      unsafeAtomicAdd(p + 1, a1);
      unsafeAtomicAdd(p + 2, a2);
      unsafeAtomicAdd(p + 3, a3);
      if (lane == 0) unsafeAtomicAdd(counts + cur, (float)runlen);
      a0 = a1 = a2 = a3 = 0.f;
      cur = g;
      runlen = 0;
    }
    const uint2 v = Hv[(size_t)n * 32 + lane];
    a0 += b2f(v.x << 16);
    a1 += b2f(v.x & 0xffff0000u);
    a2 += b2f(v.y << 16);
    a3 += b2f(v.y & 0xffff0000u);
    ++runlen;
  }
  float* p = sums + (size_t)cur * D + lane * 4;
  unsafeAtomicAdd(p + 0, a0);
  unsafeAtomicAdd(p + 1, a1);
  unsafeAtomicAdd(p + 2, a2);
  unsafeAtomicAdd(p + 3, a3);
  if (lane == 0) unsafeAtomicAdd(counts + cur, (float)runlen);
}

__global__ __launch_bounds__(256) void pool_norm_kernel(
    float* __restrict__ out, const float* __restrict__ counts, int n) {
  int i = blockIdx.x * 256 + threadIdx.x;
  if (i >= n) return;
  float cnt = counts[i / D];
  out[i] = out[i] / fmaxf(cnt, 1.0f);
}

// ---------------------------------------------------------------------------
extern "C" void kernel_launch(void* const* d_in, const int* in_sizes, int n_in,
                              void* d_out, int out_size, void* d_ws,
                              size_t ws_size, hipStream_t stream) {
  const float* x = (const float*)d_in[0];
  const int* ei = (const int*)d_in[1];
  const int* batch = (const int*)d_in[2];
  const float* B[6] = {(const float*)d_in[4],  (const float*)d_in[6],
                       (const float*)d_in[8],  (const float*)d_in[10],
                       (const float*)d_in[12], (const float*)d_in[14]};

  const int n_nodes = in_sizes[2];
  const int n_edges = in_sizes[1] / 2;
  const int n_graphs = out_size / D;
  const int* src = ei;
  const int* dst = ei + n_edges;

  const size_t matB = (size_t)n_nodes * D * sizeof(unsigned short);  // 25.6 MB
  unsigned short* bufA = (unsigned short*)d_ws;
  unsigned short* bufB = (unsigned short*)((char*)d_ws + matB);
  unsigned short* bufC = (unsigned short*)((char*)d_ws + 2 * matB);
  unsigned short* wpack = (unsigned short*)((char*)d_ws + 3 * matB);
  int* rowptr = (int*)((char*)wpack + 6 * 16384 * sizeof(unsigned short));
  int* colidx = rowptr + (n_nodes + 1);
  unsigned int* ebuf = (unsigned int*)(colidx + n_edges);
  const int NBU = (n_nodes + 255) >> 8;  // 391
  int* bcount = (int*)(ebuf + n_edges);
  int* boff = bcount + (size_t)NB_E * NBU;
  int* btot = boff + (size_t)NB_E * NBU;
  int* base = btot + NBU;
  float* counts = (float*)(base + NBU + 2);

  const dim3 blk(256);
  const int gather_blocks = (int)(((long long)n_nodes * 32 + 255) / 256);
  const int pool_groups =
      (n_nodes + POOL_NODES_PER_GROUP - 1) / POOL_NODES_PER_GROUP;
  const int pool_blocks = (pool_groups * 32 + 255) / 256;
  const int n_strips = n_nodes / 32;        // 100000 % 32 == 0
  const int mlp_grid = (n_strips + 7) / 8;  // 1 strip per wave
  const int epb = (n_edges + NB_E - 1) / NB_E;

  // ---- precompute: convert x, pack weights, counting-sort CSR ----
  convert_kernel<<<(n_nodes * (D / 8) + 255) / 256, blk, 0, stream>>>(
      x, bufA, n_nodes * (D / 8));
  pack_w6_kernel<<<48, blk, 0, stream>>>(
      (const float*)d_in[3], (const float*)d_in[5], (const float*)d_in[7],
      (const float*)d_in[9], (const float*)d_in[11], (const float*)d_in[13],
      wpack);

  bktA_kernel<<<NB_E, blk, 0, stream>>>(dst, bcount, n_edges, NBU, epb);
  bktB_kernel<<<NBU, blk, 0, stream>>>(bcount, boff, btot, NBU);
  bktBase_kernel<<<1, blk, 0, stream>>>(btot, base, NBU);
  bktC_kernel<<<NB_E, blk, 0, stream>>>(src, dst, boff, base, ebuf, n_edges,
                                        NBU, epb);
  bktD_kernel<<<NBU, blk, 0, stream>>>(ebuf, base, rowptr, colidx, n_nodes);

  // ---- layer 1 ----
  gather_bf16_kernel<<<gather_blocks, blk, 0, stream>>>(bufA, rowptr, colidx,
                                                        bufB, n_nodes);
  mlp2_kernel<1><<<mlp_grid, 512, 0, stream>>>(bufB, wpack + 0 * 16384,
                                               wpack + 1 * 16384, B[0], B[1],
                                               bufC, n_strips);
  // ---- layer 2 ----
  gather_bf16_kernel<<<gather_blocks, blk, 0, stream>>>(bufC, rowptr, colidx,
                                                        bufB, n_nodes);
  mlp2_kernel<1><<<mlp_grid, 512, 0, stream>>>(bufB, wpack + 2 * 16384,
                                               wpack + 3 * 16384, B[2], B[3],
                                               bufA, n_strips);
  // ---- layer 3 ----
  gather_bf16_kernel<<<gather_blocks, blk, 0, stream>>>(bufA, rowptr, colidx,
                                                        bufB, n_nodes);
  mlp2_kernel<0><<<mlp_grid, 512, 0, stream>>>(bufB, wpack + 4 * 16384,
                                               wpack + 5 * 16384, B[4], B[5],
                                               bufC, n_strips);

  // ---- global mean pool ----
  hipMemsetAsync(d_out, 0, (size_t)out_size * sizeof(float), stream);
  hipMemsetAsync(counts, 0, (size_t)n_graphs * sizeof(float), stream);
  pool_kernel<<<pool_blocks, blk, 0, stream>>>(bufC, batch, (float*)d_out,
                                               counts, n_nodes);
  pool_norm_kernel<<<(out_size + 255) / 256, blk, 0, stream>>>((float*)d_out,
                                                               counts,
                                                               out_size);
}